// Round 1
// baseline (363.917 us; speedup 1.0000x reference)
//
#include <hip/hip_runtime.h>
#include <hip/hip_bf16.h>
#include <math.h>

// GAT, 3 layers, N=4096, H=8, O=64, F_in=256 then 512.
// Key insight: adjacency ~1% + self loops, shared across layers -> sparse
// softmax is EXACT (masked entries underflow to 0 in fp32 softmax).
//
// ws layout:
//   [0)            nbr_cnt   : 4096 * 4            = 16 KB
//   [16384)        nbr lists : 4096 * 128 * 4      = 2 MB
//   [+2MB)         Wh        : 4096 * 512 * 4      = 8 MB
//   [+8MB)         h2        : 4096 * 512 * 4      = 8 MB
//   [+8MB)         s         : 8 * 4096 * 4        = 128 KB
//   [+128KB)       d         : 8 * 4096 * 4        = 128 KB
// total ~18.7 MB

#define NODES 4096
#define HEADS 8
#define HID   64
#define FOUT  512   // HEADS*HID
#define MAXNBR 128  // max degree; Binomial(4096,0.01) max ~70, 128 is 13 sigma

// ---------------------------------------------------------------------------
// Build fixed-width neighbor lists. One wave per row; deterministic ordering
// via ballot + prefix popcount.
// ---------------------------------------------------------------------------
__global__ __launch_bounds__(256) void build_nbr_kernel(
    const float* __restrict__ adj, int* __restrict__ nbr_cnt,
    int* __restrict__ nbr) {
  int wave = (blockIdx.x * blockDim.x + threadIdx.x) >> 6;
  int lane = threadIdx.x & 63;
  if (wave >= NODES) return;
  const float* arow = adj + (size_t)wave * NODES;
  int* lst = nbr + (size_t)wave * MAXNBR;
  int base = 0;
  for (int j0 = 0; j0 < NODES; j0 += 64) {
    float a = arow[j0 + lane];
    unsigned long long mask = __ballot(a > 0.0f);
    if (a > 0.0f) {
      int pos = base + __popcll(mask & ((1ull << lane) - 1ull));
      if (pos < MAXNBR) lst[pos] = j0 + lane;
    }
    base += __popcll(mask);
  }
  if (lane == 0) nbr_cnt[wave] = base < MAXNBR ? base : MAXNBR;
}

// ---------------------------------------------------------------------------
// C[4096, 512] = A[4096, K] * Wcat, where Wcat[f, h*64+o] = W[h, f, o].
// fp32 vector-ALU GEMM: 64x64 block tile, BK=16, 4x4 per thread, 256 threads.
// BN=64 aligns exactly to one head -> B tile is a contiguous chunk of W.
// ---------------------------------------------------------------------------
__global__ __launch_bounds__(256) void gemm_xw(
    const float* __restrict__ A,   // [4096, K]
    const float* __restrict__ W,   // [8, K, 64]
    float* __restrict__ C,         // [4096, 512]
    int K) {
  __shared__ float As[16][68];   // [BK][BM], +4 pad keeps 16B-aligned rows
  __shared__ float Bs[16][64];   // [BK][BN]

  const int t  = threadIdx.x;
  const int m0 = blockIdx.y * 64;
  const int n0 = blockIdx.x * 64;
  const int h  = blockIdx.x;               // BN==64 -> tile == one head
  const float* Wb = W + (size_t)h * K * 64;

  const int tx = t & 15;   // n sub-tile
  const int ty = t >> 4;   // m sub-tile
  const int ar = t >> 2;           // A-load row within tile (0..63)
  const int ac = (t & 3) * 4;      // A-load col (0,4,8,12)

  float acc[4][4] = {};

  for (int k0 = 0; k0 < K; k0 += 16) {
    float4 av = *(const float4*)(A + (size_t)(m0 + ar) * K + k0 + ac);
    As[ac + 0][ar] = av.x;
    As[ac + 1][ar] = av.y;
    As[ac + 2][ar] = av.z;
    As[ac + 3][ar] = av.w;
    float4 bv = *(const float4*)(Wb + (size_t)k0 * 64 + t * 4);
    *(float4*)(&Bs[0][0] + t * 4) = bv;
    __syncthreads();
#pragma unroll
    for (int kk = 0; kk < 16; ++kk) {
      float a[4], b[4];
#pragma unroll
      for (int i = 0; i < 4; ++i) a[i] = As[kk][ty * 4 + i];
#pragma unroll
      for (int j = 0; j < 4; ++j) b[j] = Bs[kk][tx * 4 + j];
#pragma unroll
      for (int i = 0; i < 4; ++i)
#pragma unroll
        for (int j = 0; j < 4; ++j) acc[i][j] += a[i] * b[j];
    }
    __syncthreads();
  }

#pragma unroll
  for (int i = 0; i < 4; ++i) {
    float4 v = make_float4(acc[i][0], acc[i][1], acc[i][2], acc[i][3]);
    *(float4*)(C + (size_t)(m0 + ty * 4 + i) * FOUT + n0 + tx * 4) = v;
  }
}

// ---------------------------------------------------------------------------
// s[h,n] = dot(Wh[n, h*64:...], a_src[h]);  d likewise. One wave per (n,h).
// ---------------------------------------------------------------------------
__global__ __launch_bounds__(256) void sd_kernel(
    const float* __restrict__ Wh, const float* __restrict__ a_src,
    const float* __restrict__ a_dst, float* __restrict__ s,
    float* __restrict__ d) {
  int wave = (blockIdx.x * blockDim.x + threadIdx.x) >> 6;
  int lane = threadIdx.x & 63;
  int n = wave >> 3;
  int h = wave & 7;
  if (n >= NODES) return;
  float w  = Wh[(size_t)n * FOUT + h * HID + lane];
  float ps = w * a_src[h * HID + lane];
  float pd = w * a_dst[h * HID + lane];
#pragma unroll
  for (int off = 32; off; off >>= 1) {
    ps += __shfl_xor(ps, off);
    pd += __shfl_xor(pd, off);
  }
  if (lane == 0) {
    s[(size_t)h * NODES + n] = ps;
    d[(size_t)h * NODES + n] = pd;
  }
}

// ---------------------------------------------------------------------------
// Sparse masked softmax + PV + ELU. Block = one row i (512 threads),
// wave = one head, lane = output dim o. Two passes over ~41 neighbors.
// ---------------------------------------------------------------------------
__global__ __launch_bounds__(512) void attn_kernel(
    const int* __restrict__ nbr_cnt, const int* __restrict__ nbr,
    const float* __restrict__ s, const float* __restrict__ d,
    const float* __restrict__ Wh, float* __restrict__ out) {
  const int i    = blockIdx.x;
  const int h    = threadIdx.x >> 6;
  const int lane = threadIdx.x & 63;
  const int cnt  = nbr_cnt[i];
  const int* lst = nbr + (size_t)i * MAXNBR;
  const float s_i = s[(size_t)h * NODES + i];
  const float* dh = d + (size_t)h * NODES;

  // pass 1: row max of leaky_relu(s_i + d_j) over neighbors
  float m = -1e30f;
  for (int t = lane; t < cnt; t += 64) {
    int j = lst[t];
    float e = s_i + dh[j];
    e = (e >= 0.0f) ? e : 0.2f * e;
    m = fmaxf(m, e);
  }
#pragma unroll
  for (int off = 32; off; off >>= 1) m = fmaxf(m, __shfl_xor(m, off));

  // pass 2: weights + gather-accumulate of Wh rows
  float denom = 0.0f, acc = 0.0f;
  for (int t = 0; t < cnt; ++t) {
    int j = lst[t];
    float e = s_i + dh[j];
    e = (e >= 0.0f) ? e : 0.2f * e;
    float w = __expf(e - m);
    denom += w;
    acc += w * Wh[(size_t)j * FOUT + h * HID + lane];
  }
  float o = acc / denom;
  o = (o > 0.0f) ? o : (__expf(o) - 1.0f);   // ELU, alpha=1
  out[(size_t)i * FOUT + h * HID + lane] = o;
}

// ---------------------------------------------------------------------------
extern "C" void kernel_launch(void* const* d_in, const int* in_sizes, int n_in,
                              void* d_out, int out_size, void* d_ws,
                              size_t ws_size, hipStream_t stream) {
  const float* features = (const float*)d_in[0];
  const float* adj      = (const float*)d_in[1];
  const float* W1  = (const float*)d_in[2];
  const float* a1s = (const float*)d_in[3];
  const float* a1d = (const float*)d_in[4];
  const float* W2  = (const float*)d_in[5];
  const float* a2s = (const float*)d_in[6];
  const float* a2d = (const float*)d_in[7];
  const float* W3  = (const float*)d_in[8];
  const float* a3s = (const float*)d_in[9];
  const float* a3d = (const float*)d_in[10];
  float* out = (float*)d_out;

  char* ws = (char*)d_ws;
  size_t off = 0;
  int* nbr_cnt = (int*)(ws + off); off += (size_t)NODES * 4;              // 16KB
  int* nbr     = (int*)(ws + off); off += (size_t)NODES * MAXNBR * 4;     // 2MB
  float* Wh    = (float*)(ws + off); off += (size_t)NODES * FOUT * 4;     // 8MB
  float* h2    = (float*)(ws + off); off += (size_t)NODES * FOUT * 4;     // 8MB
  float* sbuf  = (float*)(ws + off); off += (size_t)HEADS * NODES * 4;    // 128KB
  float* dbuf  = (float*)(ws + off); off += (size_t)HEADS * NODES * 4;    // 128KB

  build_nbr_kernel<<<NODES / 4, 256, 0, stream>>>(adj, nbr_cnt, nbr);

  dim3 gg(FOUT / 64, NODES / 64);

  // layer 1: features (K=256) -> h1 stored in d_out
  gemm_xw<<<gg, 256, 0, stream>>>(features, W1, Wh, 256);
  sd_kernel<<<NODES * HEADS / 4, 256, 0, stream>>>(Wh, a1s, a1d, sbuf, dbuf);
  attn_kernel<<<NODES, 512, 0, stream>>>(nbr_cnt, nbr, sbuf, dbuf, Wh, out);

  // layer 2: h1 (K=512) -> h2
  gemm_xw<<<gg, 256, 0, stream>>>(out, W2, Wh, 512);
  sd_kernel<<<NODES * HEADS / 4, 256, 0, stream>>>(Wh, a2s, a2d, sbuf, dbuf);
  attn_kernel<<<NODES, 512, 0, stream>>>(nbr_cnt, nbr, sbuf, dbuf, Wh, h2);

  // layer 3: h2 (K=512) -> d_out
  gemm_xw<<<gg, 256, 0, stream>>>(h2, W3, Wh, 512);
  sd_kernel<<<NODES * HEADS / 4, 256, 0, stream>>>(Wh, a3s, a3d, sbuf, dbuf);
  attn_kernel<<<NODES, 512, 0, stream>>>(nbr_cnt, nbr, sbuf, dbuf, Wh, out);
}

// Round 2
// 242.454 us; speedup vs baseline: 1.5010x; 1.5010x over previous
//
#include <hip/hip_runtime.h>
#include <hip/hip_bf16.h>
#include <math.h>

// GAT, 3 layers, N=4096, H=8, O=64, F_in=256 then 512.
// Sparse softmax over ~1%-dense adj (+self loops) is EXACT vs masked dense.
//
// R1 change: attn_kernel restructured. Weights precomputed in parallel into
// LDS (no serial scalar-load+exp chain); PV gather does 4 neighbors per wave
// iteration with float4 loads (serial trip ~41 -> ~10).

#define NODES 4096
#define HEADS 8
#define HID   64
#define FOUT  512   // HEADS*HID
#define MAXNBR 128  // max degree; Binomial(4096,0.01) max ~70, 128 is 13 sigma

// ---------------------------------------------------------------------------
// Build fixed-width neighbor lists. One wave per row; deterministic ordering
// via ballot + prefix popcount.
// ---------------------------------------------------------------------------
__global__ __launch_bounds__(256) void build_nbr_kernel(
    const float* __restrict__ adj, int* __restrict__ nbr_cnt,
    int* __restrict__ nbr) {
  int wave = (blockIdx.x * blockDim.x + threadIdx.x) >> 6;
  int lane = threadIdx.x & 63;
  if (wave >= NODES) return;
  const float* arow = adj + (size_t)wave * NODES;
  int* lst = nbr + (size_t)wave * MAXNBR;
  int base = 0;
  for (int j0 = 0; j0 < NODES; j0 += 64) {
    float a = arow[j0 + lane];
    unsigned long long mask = __ballot(a > 0.0f);
    if (a > 0.0f) {
      int pos = base + __popcll(mask & ((1ull << lane) - 1ull));
      if (pos < MAXNBR) lst[pos] = j0 + lane;
    }
    base += __popcll(mask);
  }
  if (lane == 0) nbr_cnt[wave] = base < MAXNBR ? base : MAXNBR;
}

// ---------------------------------------------------------------------------
// C[4096, 512] = A[4096, K] * Wcat, where Wcat[f, h*64+o] = W[h, f, o].
// fp32 vector-ALU GEMM: 64x64 block tile, BK=16, 4x4 per thread, 256 threads.
// ---------------------------------------------------------------------------
__global__ __launch_bounds__(256) void gemm_xw(
    const float* __restrict__ A,   // [4096, K]
    const float* __restrict__ W,   // [8, K, 64]
    float* __restrict__ C,         // [4096, 512]
    int K) {
  __shared__ float As[16][68];
  __shared__ float Bs[16][64];

  const int t  = threadIdx.x;
  const int m0 = blockIdx.y * 64;
  const int n0 = blockIdx.x * 64;
  const int h  = blockIdx.x;               // BN==64 -> tile == one head
  const float* Wb = W + (size_t)h * K * 64;

  const int tx = t & 15;
  const int ty = t >> 4;
  const int ar = t >> 2;
  const int ac = (t & 3) * 4;

  float acc[4][4] = {};

  for (int k0 = 0; k0 < K; k0 += 16) {
    float4 av = *(const float4*)(A + (size_t)(m0 + ar) * K + k0 + ac);
    As[ac + 0][ar] = av.x;
    As[ac + 1][ar] = av.y;
    As[ac + 2][ar] = av.z;
    As[ac + 3][ar] = av.w;
    float4 bv = *(const float4*)(Wb + (size_t)k0 * 64 + t * 4);
    *(float4*)(&Bs[0][0] + t * 4) = bv;
    __syncthreads();
#pragma unroll
    for (int kk = 0; kk < 16; ++kk) {
      float a[4], b[4];
#pragma unroll
      for (int i = 0; i < 4; ++i) a[i] = As[kk][ty * 4 + i];
#pragma unroll
      for (int j = 0; j < 4; ++j) b[j] = Bs[kk][tx * 4 + j];
#pragma unroll
      for (int i = 0; i < 4; ++i)
#pragma unroll
        for (int j = 0; j < 4; ++j) acc[i][j] += a[i] * b[j];
    }
    __syncthreads();
  }

#pragma unroll
  for (int i = 0; i < 4; ++i) {
    float4 v = make_float4(acc[i][0], acc[i][1], acc[i][2], acc[i][3]);
    *(float4*)(C + (size_t)(m0 + ty * 4 + i) * FOUT + n0 + tx * 4) = v;
  }
}

// ---------------------------------------------------------------------------
// s[h,n] = dot(Wh[n, h*64:...], a_src[h]);  d likewise. One wave per (n,h).
// ---------------------------------------------------------------------------
__global__ __launch_bounds__(256) void sd_kernel(
    const float* __restrict__ Wh, const float* __restrict__ a_src,
    const float* __restrict__ a_dst, float* __restrict__ s,
    float* __restrict__ d) {
  int wave = (blockIdx.x * blockDim.x + threadIdx.x) >> 6;
  int lane = threadIdx.x & 63;
  int n = wave >> 3;
  int h = wave & 7;
  if (n >= NODES) return;
  float w  = Wh[(size_t)n * FOUT + h * HID + lane];
  float ps = w * a_src[h * HID + lane];
  float pd = w * a_dst[h * HID + lane];
#pragma unroll
  for (int off = 32; off; off >>= 1) {
    ps += __shfl_xor(ps, off);
    pd += __shfl_xor(pd, off);
  }
  if (lane == 0) {
    s[(size_t)h * NODES + n] = ps;
    d[(size_t)h * NODES + n] = pd;
  }
}

// ---------------------------------------------------------------------------
// Sparse masked softmax + PV + ELU. Block = one row i (512 threads),
// wave = one head.
// Phase 1 (parallel): stage nbr list in LDS; compute e[h][t] with all 512
//   threads; per-head max + denom via shfl; weights -> LDS.
// Phase 2 (gather): wave h processes 4 neighbors/iter; lane = 16*g + dq,
//   g = neighbor subgroup (0..3), dq = dim quad. float4 loads, then
//   shfl_xor(16,32) folds the 4 subgroups.
// ---------------------------------------------------------------------------
__global__ __launch_bounds__(512) void attn_kernel(
    const int* __restrict__ nbr_cnt, const int* __restrict__ nbr,
    const float* __restrict__ s, const float* __restrict__ d,
    const float* __restrict__ Wh, float* __restrict__ out) {
  __shared__ int   lst_lds[MAXNBR];
  __shared__ float w_lds[HEADS][MAXNBR];

  const int i    = blockIdx.x;
  const int tid  = threadIdx.x;
  const int h    = tid >> 6;
  const int lane = tid & 63;
  const int cnt  = nbr_cnt[i];

  // stage neighbor list; pad with self (weight will be 0)
  if (tid < MAXNBR)
    lst_lds[tid] = (tid < cnt) ? nbr[(size_t)i * MAXNBR + tid] : i;
  __syncthreads();

  // phase 1: weights. thread (h, lane) handles t = lane and t = lane+64.
  const float s_i = s[(size_t)h * NODES + i];
  const float* dh = d + (size_t)h * NODES;
  float e0 = -1e30f, e1 = -1e30f;
  if (lane < cnt) {
    float e = s_i + dh[lst_lds[lane]];
    e0 = (e >= 0.0f) ? e : 0.2f * e;
  }
  if (lane + 64 < cnt) {
    float e = s_i + dh[lst_lds[lane + 64]];
    e1 = (e >= 0.0f) ? e : 0.2f * e;
  }
  float m = fmaxf(e0, e1);
#pragma unroll
  for (int off = 32; off; off >>= 1) m = fmaxf(m, __shfl_xor(m, off));
  float w0 = (lane < cnt) ? __expf(e0 - m) : 0.0f;
  float w1 = (lane + 64 < cnt) ? __expf(e1 - m) : 0.0f;
  w_lds[h][lane]      = w0;
  w_lds[h][lane + 64] = w1;
  float den = w0 + w1;
#pragma unroll
  for (int off = 32; off; off >>= 1) den += __shfl_xor(den, off);
  const float rden = 1.0f / den;   // uniform across wave
  __syncthreads();

  // phase 2: gather. 4 neighbors per iteration.
  const int g  = lane >> 4;          // neighbor subgroup 0..3
  const int dq = (lane & 15) * 4;    // dim quad 0,4,...,60
  const int cnt4 = (cnt + 3) & ~3;
  float ax = 0.0f, ay = 0.0f, az = 0.0f, aw = 0.0f;
  for (int t0 = 0; t0 < cnt4; t0 += 4) {
    const int   t = t0 + g;
    const int   j = lst_lds[t];          // padded -> i, weight 0
    const float w = w_lds[h][t];
    const float4 v = *(const float4*)(Wh + (size_t)j * FOUT + h * HID + dq);
    ax += w * v.x; ay += w * v.y; az += w * v.z; aw += w * v.w;
  }
  // fold subgroups: lanes l, l^16, l^32, l^48 hold same dims
  ax += __shfl_xor(ax, 16); ax += __shfl_xor(ax, 32);
  ay += __shfl_xor(ay, 16); ay += __shfl_xor(ay, 32);
  az += __shfl_xor(az, 16); az += __shfl_xor(az, 32);
  aw += __shfl_xor(aw, 16); aw += __shfl_xor(aw, 32);

  if (lane < 16) {
    float4 o;
    o.x = ax * rden; o.y = ay * rden; o.z = az * rden; o.w = aw * rden;
    o.x = (o.x > 0.0f) ? o.x : (__expf(o.x) - 1.0f);
    o.y = (o.y > 0.0f) ? o.y : (__expf(o.y) - 1.0f);
    o.z = (o.z > 0.0f) ? o.z : (__expf(o.z) - 1.0f);
    o.w = (o.w > 0.0f) ? o.w : (__expf(o.w) - 1.0f);
    *(float4*)(out + (size_t)i * FOUT + h * HID + dq) = o;
  }
}

// ---------------------------------------------------------------------------
extern "C" void kernel_launch(void* const* d_in, const int* in_sizes, int n_in,
                              void* d_out, int out_size, void* d_ws,
                              size_t ws_size, hipStream_t stream) {
  const float* features = (const float*)d_in[0];
  const float* adj      = (const float*)d_in[1];
  const float* W1  = (const float*)d_in[2];
  const float* a1s = (const float*)d_in[3];
  const float* a1d = (const float*)d_in[4];
  const float* W2  = (const float*)d_in[5];
  const float* a2s = (const float*)d_in[6];
  const float* a2d = (const float*)d_in[7];
  const float* W3  = (const float*)d_in[8];
  const float* a3s = (const float*)d_in[9];
  const float* a3d = (const float*)d_in[10];
  float* out = (float*)d_out;

  char* ws = (char*)d_ws;
  size_t off = 0;
  int* nbr_cnt = (int*)(ws + off); off += (size_t)NODES * 4;
  int* nbr     = (int*)(ws + off); off += (size_t)NODES * MAXNBR * 4;
  float* Wh    = (float*)(ws + off); off += (size_t)NODES * FOUT * 4;
  float* h2    = (float*)(ws + off); off += (size_t)NODES * FOUT * 4;
  float* sbuf  = (float*)(ws + off); off += (size_t)HEADS * NODES * 4;
  float* dbuf  = (float*)(ws + off); off += (size_t)HEADS * NODES * 4;

  build_nbr_kernel<<<NODES / 4, 256, 0, stream>>>(adj, nbr_cnt, nbr);

  dim3 gg(FOUT / 64, NODES / 64);

  gemm_xw<<<gg, 256, 0, stream>>>(features, W1, Wh, 256);
  sd_kernel<<<NODES * HEADS / 4, 256, 0, stream>>>(Wh, a1s, a1d, sbuf, dbuf);
  attn_kernel<<<NODES, 512, 0, stream>>>(nbr_cnt, nbr, sbuf, dbuf, Wh, out);

  gemm_xw<<<gg, 256, 0, stream>>>(out, W2, Wh, 512);
  sd_kernel<<<NODES * HEADS / 4, 256, 0, stream>>>(Wh, a2s, a2d, sbuf, dbuf);
  attn_kernel<<<NODES, 512, 0, stream>>>(nbr_cnt, nbr, sbuf, dbuf, Wh, h2);

  gemm_xw<<<gg, 256, 0, stream>>>(h2, W3, Wh, 512);
  sd_kernel<<<NODES * HEADS / 4, 256, 0, stream>>>(Wh, a3s, a3d, sbuf, dbuf);
  attn_kernel<<<NODES, 512, 0, stream>>>(nbr_cnt, nbr, sbuf, dbuf, Wh, out);
}

// Round 3
// 229.128 us; speedup vs baseline: 1.5883x; 1.0582x over previous
//
#include <hip/hip_runtime.h>
#include <hip/hip_bf16.h>
#include <math.h>

// GAT, 3 layers, N=4096, H=8, O=64, F_in=256 then 512.
// Sparse softmax over ~1%-dense adj (+self loops) is EXACT vs masked dense.
//
// R2 change: GEMM moved to MFMA via exact fp16 hi/lo split-K trick:
//   A*B ~= Ah*Bh + Al*Bh + Ah*Bl  (drop Al*Bl ~ 2^-22 rel)
// done as ONE fp16 GEMM with K_eff=3K: A_cat=[Ah|Al|Ah], B_cat=[Bh;Bh;Bl],
// B stored transposed [n][k] so A and B fragments are both contiguous
// ds_read_b128 with identical lane->k addressing (k-permutation cancels).

#define NODES 4096
#define HEADS 8
#define HID   64
#define FOUT  512   // HEADS*HID
#define MAXNBR 128

typedef _Float16 half8 __attribute__((ext_vector_type(8)));
typedef _Float16 half4 __attribute__((ext_vector_type(4)));
typedef float f32x4 __attribute__((ext_vector_type(4)));

// ---------------------------------------------------------------------------
__global__ __launch_bounds__(256) void build_nbr_kernel(
    const float* __restrict__ adj, int* __restrict__ nbr_cnt,
    int* __restrict__ nbr) {
  int wave = (blockIdx.x * blockDim.x + threadIdx.x) >> 6;
  int lane = threadIdx.x & 63;
  if (wave >= NODES) return;
  const float* arow = adj + (size_t)wave * NODES;
  int* lst = nbr + (size_t)wave * MAXNBR;
  int base = 0;
  for (int j0 = 0; j0 < NODES; j0 += 64) {
    float a = arow[j0 + lane];
    unsigned long long mask = __ballot(a > 0.0f);
    if (a > 0.0f) {
      int pos = base + __popcll(mask & ((1ull << lane) - 1ull));
      if (pos < MAXNBR) lst[pos] = j0 + lane;
    }
    base += __popcll(mask);
  }
  if (lane == 0) nbr_cnt[wave] = base < MAXNBR ? base : MAXNBR;
}

// ---------------------------------------------------------------------------
// A [4096][K] fp32 -> Ac [4096][3K] fp16 = [Ah | Al | Ah]
// ---------------------------------------------------------------------------
__global__ __launch_bounds__(256) void convA_kernel(
    const float* __restrict__ in, _Float16* __restrict__ out, int K) {
  int perRow = K >> 2;
  int id = blockIdx.x * blockDim.x + threadIdx.x;
  if (id >= NODES * perRow) return;
  int m = id / perRow, c = (id - m * perRow) * 4;
  float4 v = *(const float4*)(in + (size_t)m * K + c);
  half4 hi, lo;
  hi[0] = (_Float16)v.x; lo[0] = (_Float16)(v.x - (float)hi[0]);
  hi[1] = (_Float16)v.y; lo[1] = (_Float16)(v.y - (float)hi[1]);
  hi[2] = (_Float16)v.z; lo[2] = (_Float16)(v.z - (float)hi[2]);
  hi[3] = (_Float16)v.w; lo[3] = (_Float16)(v.w - (float)hi[3]);
  _Float16* rb = out + (size_t)m * 3 * K;
  *(half4*)(rb + c)         = hi;
  *(half4*)(rb + K + c)     = lo;
  *(half4*)(rb + 2 * K + c) = hi;
}

// ---------------------------------------------------------------------------
// W [8][K][64] fp32 -> Bc [512][3K] fp16, row = h*64+n, sections [Bh|Bh|Bl]
// ---------------------------------------------------------------------------
__global__ __launch_bounds__(256) void convW_kernel(
    const float* __restrict__ W, _Float16* __restrict__ Bc, int K) {
  int id = blockIdx.x * blockDim.x + threadIdx.x;
  int total = HEADS * 64 * (K >> 3);
  if (id >= total) return;
  int n = id & 63;
  int r = id >> 6;
  int kchunks = K >> 3;
  int kc = r % kchunks, h = r / kchunks;
  int k0 = kc * 8;
  half8 hi, lo;
#pragma unroll
  for (int i = 0; i < 8; ++i) {
    float w = W[((size_t)h * K + k0 + i) * 64 + n];
    _Float16 wh = (_Float16)w;
    hi[i] = wh;
    lo[i] = (_Float16)(w - (float)wh);
  }
  _Float16* rb = Bc + (size_t)(h * 64 + n) * (3 * K);
  *(half8*)(rb + k0)         = hi;
  *(half8*)(rb + K + k0)     = hi;
  *(half8*)(rb + 2 * K + k0) = lo;
}

// ---------------------------------------------------------------------------
// C[4096,512] = Ac[4096,Keff] * Bc[512,Keff]^T   (fp16 in, fp32 out)
// 64x64 tile, BK=32, 4 waves, each wave 32x32 = 2x2 frags of 16x16x32 MFMA.
// LDS pitch 40 halfs (80B) -> 2-way bank aliasing only (free).
// ---------------------------------------------------------------------------
__global__ __launch_bounds__(256) void gemm_mfma(
    const _Float16* __restrict__ A,   // [4096][Keff]
    const _Float16* __restrict__ B,   // [512][Keff]  (n-major)
    float* __restrict__ C,            // [4096][512]
    int Keff) {
  __shared__ _Float16 As[64 * 40];
  __shared__ _Float16 Bs[64 * 40];

  const int t    = threadIdx.x;
  const int m0   = blockIdx.y * 64;
  const int n0   = blockIdx.x * 64;
  const int w    = t >> 6;
  const int lane = t & 63;
  const int wr   = (w >> 1) * 32;   // wave row offset in tile
  const int wc   = (w & 1) * 32;    // wave col offset
  const int lr   = lane & 15;
  const int lk   = (lane >> 4) * 8;

  const int sr = t >> 2;            // staging row 0..63
  const int sc = (t & 3) * 8;       // staging col (halfs)
  const _Float16* gA = A + (size_t)(m0 + sr) * Keff + sc;
  const _Float16* gB = B + (size_t)(n0 + sr) * Keff + sc;

  f32x4 acc00 = {}, acc01 = {}, acc10 = {}, acc11 = {};

  half8 av = *(const half8*)(gA);
  half8 bv = *(const half8*)(gB);

  for (int k0 = 0; k0 < Keff; k0 += 32) {
    __syncthreads();
    *(half8*)(&As[sr * 40 + sc]) = av;
    *(half8*)(&Bs[sr * 40 + sc]) = bv;
    __syncthreads();
    if (k0 + 32 < Keff) {
      av = *(const half8*)(gA + k0 + 32);
      bv = *(const half8*)(gB + k0 + 32);
    }
    half8 a0 = *(const half8*)(&As[(wr + lr) * 40 + lk]);
    half8 a1 = *(const half8*)(&As[(wr + 16 + lr) * 40 + lk]);
    half8 b0 = *(const half8*)(&Bs[(wc + lr) * 40 + lk]);
    half8 b1 = *(const half8*)(&Bs[(wc + 16 + lr) * 40 + lk]);
    acc00 = __builtin_amdgcn_mfma_f32_16x16x32_f16(a0, b0, acc00, 0, 0, 0);
    acc01 = __builtin_amdgcn_mfma_f32_16x16x32_f16(a0, b1, acc01, 0, 0, 0);
    acc10 = __builtin_amdgcn_mfma_f32_16x16x32_f16(a1, b0, acc10, 0, 0, 0);
    acc11 = __builtin_amdgcn_mfma_f32_16x16x32_f16(a1, b1, acc11, 0, 0, 0);
  }

  // C/D layout: col = lane&15, row = (lane>>4)*4 + reg  [m89/m91 verified]
  const int cm = (lane >> 4) * 4;
#pragma unroll
  for (int j = 0; j < 4; ++j) {
    int m = m0 + wr + cm + j;
    C[(size_t)m * FOUT + n0 + wc + lr]      = acc00[j];
    C[(size_t)m * FOUT + n0 + wc + 16 + lr] = acc01[j];
    int m2 = m + 16;
    C[(size_t)m2 * FOUT + n0 + wc + lr]      = acc10[j];
    C[(size_t)m2 * FOUT + n0 + wc + 16 + lr] = acc11[j];
  }
}

// ---------------------------------------------------------------------------
__global__ __launch_bounds__(256) void sd_kernel(
    const float* __restrict__ Wh, const float* __restrict__ a_src,
    const float* __restrict__ a_dst, float* __restrict__ s,
    float* __restrict__ d) {
  int wave = (blockIdx.x * blockDim.x + threadIdx.x) >> 6;
  int lane = threadIdx.x & 63;
  int n = wave >> 3;
  int h = wave & 7;
  if (n >= NODES) return;
  float w  = Wh[(size_t)n * FOUT + h * HID + lane];
  float ps = w * a_src[h * HID + lane];
  float pd = w * a_dst[h * HID + lane];
#pragma unroll
  for (int off = 32; off; off >>= 1) {
    ps += __shfl_xor(ps, off);
    pd += __shfl_xor(pd, off);
  }
  if (lane == 0) {
    s[(size_t)h * NODES + n] = ps;
    d[(size_t)h * NODES + n] = pd;
  }
}

// ---------------------------------------------------------------------------
__global__ __launch_bounds__(512) void attn_kernel(
    const int* __restrict__ nbr_cnt, const int* __restrict__ nbr,
    const float* __restrict__ s, const float* __restrict__ d,
    const float* __restrict__ Wh, float* __restrict__ out) {
  __shared__ int   lst_lds[MAXNBR];
  __shared__ float w_lds[HEADS][MAXNBR];

  const int i    = blockIdx.x;
  const int tid  = threadIdx.x;
  const int h    = tid >> 6;
  const int lane = tid & 63;
  const int cnt  = nbr_cnt[i];

  if (tid < MAXNBR)
    lst_lds[tid] = (tid < cnt) ? nbr[(size_t)i * MAXNBR + tid] : i;
  __syncthreads();

  const float s_i = s[(size_t)h * NODES + i];
  const float* dh = d + (size_t)h * NODES;
  float e0 = -1e30f, e1 = -1e30f;
  if (lane < cnt) {
    float e = s_i + dh[lst_lds[lane]];
    e0 = (e >= 0.0f) ? e : 0.2f * e;
  }
  if (lane + 64 < cnt) {
    float e = s_i + dh[lst_lds[lane + 64]];
    e1 = (e >= 0.0f) ? e : 0.2f * e;
  }
  float m = fmaxf(e0, e1);
#pragma unroll
  for (int off = 32; off; off >>= 1) m = fmaxf(m, __shfl_xor(m, off));
  float w0 = (lane < cnt) ? __expf(e0 - m) : 0.0f;
  float w1 = (lane + 64 < cnt) ? __expf(e1 - m) : 0.0f;
  w_lds[h][lane]      = w0;
  w_lds[h][lane + 64] = w1;
  float den = w0 + w1;
#pragma unroll
  for (int off = 32; off; off >>= 1) den += __shfl_xor(den, off);
  const float rden = 1.0f / den;
  __syncthreads();

  const int g  = lane >> 4;
  const int dq = (lane & 15) * 4;
  const int cnt4 = (cnt + 3) & ~3;
  float ax = 0.0f, ay = 0.0f, az = 0.0f, aw = 0.0f;
  for (int t0 = 0; t0 < cnt4; t0 += 4) {
    const int   t = t0 + g;
    const int   j = lst_lds[t];
    const float w = w_lds[h][t];
    const float4 v = *(const float4*)(Wh + (size_t)j * FOUT + h * HID + dq);
    ax += w * v.x; ay += w * v.y; az += w * v.z; aw += w * v.w;
  }
  ax += __shfl_xor(ax, 16); ax += __shfl_xor(ax, 32);
  ay += __shfl_xor(ay, 16); ay += __shfl_xor(ay, 32);
  az += __shfl_xor(az, 16); az += __shfl_xor(az, 32);
  aw += __shfl_xor(aw, 16); aw += __shfl_xor(aw, 32);

  if (lane < 16) {
    float4 o;
    o.x = ax * rden; o.y = ay * rden; o.z = az * rden; o.w = aw * rden;
    o.x = (o.x > 0.0f) ? o.x : (__expf(o.x) - 1.0f);
    o.y = (o.y > 0.0f) ? o.y : (__expf(o.y) - 1.0f);
    o.z = (o.z > 0.0f) ? o.z : (__expf(o.z) - 1.0f);
    o.w = (o.w > 0.0f) ? o.w : (__expf(o.w) - 1.0f);
    *(float4*)(out + (size_t)i * FOUT + h * HID + dq) = o;
  }
}

// ---------------------------------------------------------------------------
extern "C" void kernel_launch(void* const* d_in, const int* in_sizes, int n_in,
                              void* d_out, int out_size, void* d_ws,
                              size_t ws_size, hipStream_t stream) {
  const float* features = (const float*)d_in[0];
  const float* adj      = (const float*)d_in[1];
  const float* W1  = (const float*)d_in[2];
  const float* a1s = (const float*)d_in[3];
  const float* a1d = (const float*)d_in[4];
  const float* W2  = (const float*)d_in[5];
  const float* a2s = (const float*)d_in[6];
  const float* a2d = (const float*)d_in[7];
  const float* W3  = (const float*)d_in[8];
  const float* a3s = (const float*)d_in[9];
  const float* a3d = (const float*)d_in[10];
  float* out = (float*)d_out;

  char* ws = (char*)d_ws;
  size_t off = 0;
  int* nbr_cnt = (int*)(ws + off); off += (size_t)NODES * 4;
  int* nbr     = (int*)(ws + off); off += (size_t)NODES * MAXNBR * 4;
  float* Wh    = (float*)(ws + off); off += (size_t)NODES * FOUT * 4;
  float* h2    = (float*)(ws + off); off += (size_t)NODES * FOUT * 4;
  float* sbuf  = (float*)(ws + off); off += (size_t)HEADS * NODES * 4;
  float* dbuf  = (float*)(ws + off); off += (size_t)HEADS * NODES * 4;
  _Float16* Ac = (_Float16*)(ws + off); off += (size_t)NODES * 3 * 512 * 2; // 12MB max
  _Float16* Bc = (_Float16*)(ws + off); off += (size_t)FOUT * 3 * 512 * 2;  // 1.5MB max

  build_nbr_kernel<<<NODES / 4, 256, 0, stream>>>(adj, nbr_cnt, nbr);

  dim3 gg(HEADS, NODES / 64);

  // ---- layer 1 (K=256, Keff=768) ----
  {
    const int K = 256, Keff = 3 * K;
    convA_kernel<<<(NODES * (K / 4) + 255) / 256, 256, 0, stream>>>(features, Ac, K);
    convW_kernel<<<(HEADS * 64 * (K / 8) + 255) / 256, 256, 0, stream>>>(W1, Bc, K);
    gemm_mfma<<<gg, 256, 0, stream>>>(Ac, Bc, Wh, Keff);
    sd_kernel<<<NODES * HEADS / 4, 256, 0, stream>>>(Wh, a1s, a1d, sbuf, dbuf);
    attn_kernel<<<NODES, 512, 0, stream>>>(nbr_cnt, nbr, sbuf, dbuf, Wh, out);
  }
  // ---- layer 2 (K=512, Keff=1536) ----
  {
    const int K = 512, Keff = 3 * K;
    convA_kernel<<<(NODES * (K / 4) + 255) / 256, 256, 0, stream>>>(out, Ac, K);
    convW_kernel<<<(HEADS * 64 * (K / 8) + 255) / 256, 256, 0, stream>>>(W2, Bc, K);
    gemm_mfma<<<gg, 256, 0, stream>>>(Ac, Bc, Wh, Keff);
    sd_kernel<<<NODES * HEADS / 4, 256, 0, stream>>>(Wh, a2s, a2d, sbuf, dbuf);
    attn_kernel<<<NODES, 512, 0, stream>>>(nbr_cnt, nbr, sbuf, dbuf, Wh, h2);
  }
  // ---- layer 3 (K=512, Keff=1536) ----
  {
    const int K = 512, Keff = 3 * K;
    convA_kernel<<<(NODES * (K / 4) + 255) / 256, 256, 0, stream>>>(h2, Ac, K);
    convW_kernel<<<(HEADS * 64 * (K / 8) + 255) / 256, 256, 0, stream>>>(W3, Bc, K);
    gemm_mfma<<<gg, 256, 0, stream>>>(Ac, Bc, Wh, Keff);
    sd_kernel<<<NODES * HEADS / 4, 256, 0, stream>>>(Wh, a3s, a3d, sbuf, dbuf);
    attn_kernel<<<NODES, 512, 0, stream>>>(nbr_cnt, nbr, sbuf, dbuf, Wh, out);
  }
}

// Round 4
// 216.069 us; speedup vs baseline: 1.6843x; 1.0604x over previous
//
#include <hip/hip_runtime.h>
#include <hip/hip_bf16.h>
#include <math.h>

// GAT, 3 layers, N=4096, H=8, O=64, F_in=256 then 512.
// Sparse softmax over ~1%-dense adj (+self loops) is EXACT vs masked dense.
//
// R2: GEMM on MFMA via exact fp16 hi/lo split (A*B = Ah*Bh + Al*Bh + Ah*Bl,
//     one fp16 GEMM with Keff=3K; B transposed so both frags are b128 reads).
// R3: build_nbr vectorized to float4 (16 wave-iters, prefetched) — was
//     issue-bound at 43us; convA fused into attn epilogue for layers 2,3.

#define NODES 4096
#define HEADS 8
#define HID   64
#define FOUT  512   // HEADS*HID
#define MAXNBR 128

typedef _Float16 half8 __attribute__((ext_vector_type(8)));
typedef _Float16 half4 __attribute__((ext_vector_type(4)));
typedef float f32x4 __attribute__((ext_vector_type(4)));

// ---------------------------------------------------------------------------
// Neighbor lists. One wave per row, float4 per lane (256 cols/iter).
// Order is component-interleaved (deterministic; softmax is order-invariant
// up to fp rounding, and weights/list always consistent).
// ---------------------------------------------------------------------------
__global__ __launch_bounds__(256) void build_nbr_kernel(
    const float* __restrict__ adj, int* __restrict__ nbr_cnt,
    int* __restrict__ nbr) {
  int wave = (blockIdx.x * blockDim.x + threadIdx.x) >> 6;
  int lane = threadIdx.x & 63;
  if (wave >= NODES) return;
  const float4* arow = (const float4*)(adj + (size_t)wave * NODES);
  int* lst = nbr + (size_t)wave * MAXNBR;
  int base = 0;
  float4 a = arow[lane];
#pragma unroll 4
  for (int it = 0; it < 16; ++it) {
    float4 cur = a;
    if (it + 1 < 16) a = arow[(it + 1) * 64 + lane];
    const int colbase = it * 256 + lane * 4;
#pragma unroll
    for (int c = 0; c < 4; ++c) {
      float v = (c == 0) ? cur.x : (c == 1) ? cur.y : (c == 2) ? cur.z : cur.w;
      unsigned long long mask = __ballot(v > 0.0f);
      if (v > 0.0f) {
        int pos = base + __popcll(mask & ((1ull << lane) - 1ull));
        if (pos < MAXNBR) lst[pos] = colbase + c;
      }
      base += __popcll(mask);
    }
  }
  if (lane == 0) nbr_cnt[wave] = base < MAXNBR ? base : MAXNBR;
}

// ---------------------------------------------------------------------------
// A [4096][K] fp32 -> Ac [4096][3K] fp16 = [Ah | Al | Ah]   (layer 1 only)
// ---------------------------------------------------------------------------
__global__ __launch_bounds__(256) void convA_kernel(
    const float* __restrict__ in, _Float16* __restrict__ out, int K) {
  int perRow = K >> 2;
  int id = blockIdx.x * blockDim.x + threadIdx.x;
  if (id >= NODES * perRow) return;
  int m = id / perRow, c = (id - m * perRow) * 4;
  float4 v = *(const float4*)(in + (size_t)m * K + c);
  half4 hi, lo;
  hi[0] = (_Float16)v.x; lo[0] = (_Float16)(v.x - (float)hi[0]);
  hi[1] = (_Float16)v.y; lo[1] = (_Float16)(v.y - (float)hi[1]);
  hi[2] = (_Float16)v.z; lo[2] = (_Float16)(v.z - (float)hi[2]);
  hi[3] = (_Float16)v.w; lo[3] = (_Float16)(v.w - (float)hi[3]);
  _Float16* rb = out + (size_t)m * 3 * K;
  *(half4*)(rb + c)         = hi;
  *(half4*)(rb + K + c)     = lo;
  *(half4*)(rb + 2 * K + c) = hi;
}

// ---------------------------------------------------------------------------
// W [8][K][64] fp32 -> Bc [512][3K] fp16, row = h*64+n, sections [Bh|Bh|Bl]
// ---------------------------------------------------------------------------
__global__ __launch_bounds__(256) void convW_kernel(
    const float* __restrict__ W, _Float16* __restrict__ Bc, int K) {
  int id = blockIdx.x * blockDim.x + threadIdx.x;
  int total = HEADS * 64 * (K >> 3);
  if (id >= total) return;
  int n = id & 63;
  int r = id >> 6;
  int kchunks = K >> 3;
  int kc = r % kchunks, h = r / kchunks;
  int k0 = kc * 8;
  half8 hi, lo;
#pragma unroll
  for (int i = 0; i < 8; ++i) {
    float w = W[((size_t)h * K + k0 + i) * 64 + n];
    _Float16 wh = (_Float16)w;
    hi[i] = wh;
    lo[i] = (_Float16)(w - (float)wh);
  }
  _Float16* rb = Bc + (size_t)(h * 64 + n) * (3 * K);
  *(half8*)(rb + k0)         = hi;
  *(half8*)(rb + K + k0)     = hi;
  *(half8*)(rb + 2 * K + k0) = lo;
}

// ---------------------------------------------------------------------------
// C[4096,512] = Ac[4096,Keff] * Bc[512,Keff]^T   (fp16 in, fp32 out)
// 64x64 tile, BK=32, 4 waves, each wave 32x32 = 2x2 frags of 16x16x32 MFMA.
// ---------------------------------------------------------------------------
__global__ __launch_bounds__(256) void gemm_mfma(
    const _Float16* __restrict__ A,   // [4096][Keff]
    const _Float16* __restrict__ B,   // [512][Keff]  (n-major)
    float* __restrict__ C,            // [4096][512]
    int Keff) {
  __shared__ _Float16 As[64 * 40];
  __shared__ _Float16 Bs[64 * 40];

  const int t    = threadIdx.x;
  const int m0   = blockIdx.y * 64;
  const int n0   = blockIdx.x * 64;
  const int w    = t >> 6;
  const int lane = t & 63;
  const int wr   = (w >> 1) * 32;
  const int wc   = (w & 1) * 32;
  const int lr   = lane & 15;
  const int lk   = (lane >> 4) * 8;

  const int sr = t >> 2;
  const int sc = (t & 3) * 8;
  const _Float16* gA = A + (size_t)(m0 + sr) * Keff + sc;
  const _Float16* gB = B + (size_t)(n0 + sr) * Keff + sc;

  f32x4 acc00 = {}, acc01 = {}, acc10 = {}, acc11 = {};

  half8 av = *(const half8*)(gA);
  half8 bv = *(const half8*)(gB);

  for (int k0 = 0; k0 < Keff; k0 += 32) {
    __syncthreads();
    *(half8*)(&As[sr * 40 + sc]) = av;
    *(half8*)(&Bs[sr * 40 + sc]) = bv;
    __syncthreads();
    if (k0 + 32 < Keff) {
      av = *(const half8*)(gA + k0 + 32);
      bv = *(const half8*)(gB + k0 + 32);
    }
    half8 a0 = *(const half8*)(&As[(wr + lr) * 40 + lk]);
    half8 a1 = *(const half8*)(&As[(wr + 16 + lr) * 40 + lk]);
    half8 b0 = *(const half8*)(&Bs[(wc + lr) * 40 + lk]);
    half8 b1 = *(const half8*)(&Bs[(wc + 16 + lr) * 40 + lk]);
    acc00 = __builtin_amdgcn_mfma_f32_16x16x32_f16(a0, b0, acc00, 0, 0, 0);
    acc01 = __builtin_amdgcn_mfma_f32_16x16x32_f16(a0, b1, acc01, 0, 0, 0);
    acc10 = __builtin_amdgcn_mfma_f32_16x16x32_f16(a1, b0, acc10, 0, 0, 0);
    acc11 = __builtin_amdgcn_mfma_f32_16x16x32_f16(a1, b1, acc11, 0, 0, 0);
  }

  const int cm = (lane >> 4) * 4;
#pragma unroll
  for (int j = 0; j < 4; ++j) {
    int m = m0 + wr + cm + j;
    C[(size_t)m * FOUT + n0 + wc + lr]      = acc00[j];
    C[(size_t)m * FOUT + n0 + wc + 16 + lr] = acc01[j];
    int m2 = m + 16;
    C[(size_t)m2 * FOUT + n0 + wc + lr]      = acc10[j];
    C[(size_t)m2 * FOUT + n0 + wc + 16 + lr] = acc11[j];
  }
}

// ---------------------------------------------------------------------------
__global__ __launch_bounds__(256) void sd_kernel(
    const float* __restrict__ Wh, const float* __restrict__ a_src,
    const float* __restrict__ a_dst, float* __restrict__ s,
    float* __restrict__ d) {
  int wave = (blockIdx.x * blockDim.x + threadIdx.x) >> 6;
  int lane = threadIdx.x & 63;
  int n = wave >> 3;
  int h = wave & 7;
  if (n >= NODES) return;
  float w  = Wh[(size_t)n * FOUT + h * HID + lane];
  float ps = w * a_src[h * HID + lane];
  float pd = w * a_dst[h * HID + lane];
#pragma unroll
  for (int off = 32; off; off >>= 1) {
    ps += __shfl_xor(ps, off);
    pd += __shfl_xor(pd, off);
  }
  if (lane == 0) {
    s[(size_t)h * NODES + n] = ps;
    d[(size_t)h * NODES + n] = pd;
  }
}

// ---------------------------------------------------------------------------
// Sparse masked softmax + PV + ELU. Optionally also emits the next layer's
// fp16 hi/lo split A (WRITE_AC) so the standalone convA pass is skipped.
// ---------------------------------------------------------------------------
template <int WRITE_AC>
__global__ __launch_bounds__(512) void attn_kernel(
    const int* __restrict__ nbr_cnt, const int* __restrict__ nbr,
    const float* __restrict__ s, const float* __restrict__ d,
    const float* __restrict__ Wh, float* __restrict__ out,
    _Float16* __restrict__ Ac) {   // [4096][3*512] when WRITE_AC
  __shared__ int   lst_lds[MAXNBR];
  __shared__ float w_lds[HEADS][MAXNBR];

  const int i    = blockIdx.x;
  const int tid  = threadIdx.x;
  const int h    = tid >> 6;
  const int lane = tid & 63;
  const int cnt  = nbr_cnt[i];

  if (tid < MAXNBR)
    lst_lds[tid] = (tid < cnt) ? nbr[(size_t)i * MAXNBR + tid] : i;
  __syncthreads();

  const float s_i = s[(size_t)h * NODES + i];
  const float* dh = d + (size_t)h * NODES;
  float e0 = -1e30f, e1 = -1e30f;
  if (lane < cnt) {
    float e = s_i + dh[lst_lds[lane]];
    e0 = (e >= 0.0f) ? e : 0.2f * e;
  }
  if (lane + 64 < cnt) {
    float e = s_i + dh[lst_lds[lane + 64]];
    e1 = (e >= 0.0f) ? e : 0.2f * e;
  }
  float m = fmaxf(e0, e1);
#pragma unroll
  for (int off = 32; off; off >>= 1) m = fmaxf(m, __shfl_xor(m, off));
  float w0 = (lane < cnt) ? __expf(e0 - m) : 0.0f;
  float w1 = (lane + 64 < cnt) ? __expf(e1 - m) : 0.0f;
  w_lds[h][lane]      = w0;
  w_lds[h][lane + 64] = w1;
  float den = w0 + w1;
#pragma unroll
  for (int off = 32; off; off >>= 1) den += __shfl_xor(den, off);
  const float rden = 1.0f / den;
  __syncthreads();

  const int g  = lane >> 4;
  const int dq = (lane & 15) * 4;
  const int cnt4 = (cnt + 3) & ~3;
  float ax = 0.0f, ay = 0.0f, az = 0.0f, aw = 0.0f;
  for (int t0 = 0; t0 < cnt4; t0 += 4) {
    const int   t = t0 + g;
    const int   j = lst_lds[t];
    const float w = w_lds[h][t];
    const float4 v = *(const float4*)(Wh + (size_t)j * FOUT + h * HID + dq);
    ax += w * v.x; ay += w * v.y; az += w * v.z; aw += w * v.w;
  }
  ax += __shfl_xor(ax, 16); ax += __shfl_xor(ax, 32);
  ay += __shfl_xor(ay, 16); ay += __shfl_xor(ay, 32);
  az += __shfl_xor(az, 16); az += __shfl_xor(az, 32);
  aw += __shfl_xor(aw, 16); aw += __shfl_xor(aw, 32);

  if (lane < 16) {
    float4 o;
    o.x = ax * rden; o.y = ay * rden; o.z = az * rden; o.w = aw * rden;
    o.x = (o.x > 0.0f) ? o.x : (__expf(o.x) - 1.0f);
    o.y = (o.y > 0.0f) ? o.y : (__expf(o.y) - 1.0f);
    o.z = (o.z > 0.0f) ? o.z : (__expf(o.z) - 1.0f);
    o.w = (o.w > 0.0f) ? o.w : (__expf(o.w) - 1.0f);
    *(float4*)(out + (size_t)i * FOUT + h * HID + dq) = o;
    if (WRITE_AC) {
      const int K = FOUT;  // next layer K = 512
      half4 hi, lo;
      hi[0] = (_Float16)o.x; lo[0] = (_Float16)(o.x - (float)hi[0]);
      hi[1] = (_Float16)o.y; lo[1] = (_Float16)(o.y - (float)hi[1]);
      hi[2] = (_Float16)o.z; lo[2] = (_Float16)(o.z - (float)hi[2]);
      hi[3] = (_Float16)o.w; lo[3] = (_Float16)(o.w - (float)hi[3]);
      _Float16* rb = Ac + (size_t)i * 3 * K + h * HID + dq;
      *(half4*)(rb)         = hi;
      *(half4*)(rb + K)     = lo;
      *(half4*)(rb + 2 * K) = hi;
    }
  }
}

// ---------------------------------------------------------------------------
extern "C" void kernel_launch(void* const* d_in, const int* in_sizes, int n_in,
                              void* d_out, int out_size, void* d_ws,
                              size_t ws_size, hipStream_t stream) {
  const float* features = (const float*)d_in[0];
  const float* adj      = (const float*)d_in[1];
  const float* W1  = (const float*)d_in[2];
  const float* a1s = (const float*)d_in[3];
  const float* a1d = (const float*)d_in[4];
  const float* W2  = (const float*)d_in[5];
  const float* a2s = (const float*)d_in[6];
  const float* a2d = (const float*)d_in[7];
  const float* W3  = (const float*)d_in[8];
  const float* a3s = (const float*)d_in[9];
  const float* a3d = (const float*)d_in[10];
  float* out = (float*)d_out;

  char* ws = (char*)d_ws;
  size_t off = 0;
  int* nbr_cnt = (int*)(ws + off); off += (size_t)NODES * 4;
  int* nbr     = (int*)(ws + off); off += (size_t)NODES * MAXNBR * 4;
  float* Wh    = (float*)(ws + off); off += (size_t)NODES * FOUT * 4;
  float* h2    = (float*)(ws + off); off += (size_t)NODES * FOUT * 4;
  float* sbuf  = (float*)(ws + off); off += (size_t)HEADS * NODES * 4;
  float* dbuf  = (float*)(ws + off); off += (size_t)HEADS * NODES * 4;
  _Float16* Ac = (_Float16*)(ws + off); off += (size_t)NODES * 3 * 512 * 2;
  _Float16* Bc = (_Float16*)(ws + off); off += (size_t)FOUT * 3 * 512 * 2;

  build_nbr_kernel<<<NODES / 4, 256, 0, stream>>>(adj, nbr_cnt, nbr);

  dim3 gg(HEADS, NODES / 64);

  // ---- layer 1 (K=256, Keff=768) ----
  {
    const int K = 256, Keff = 3 * K;
    convA_kernel<<<(NODES * (K / 4) + 255) / 256, 256, 0, stream>>>(features, Ac, K);
    convW_kernel<<<(HEADS * 64 * (K / 8) + 255) / 256, 256, 0, stream>>>(W1, Bc, K);
    gemm_mfma<<<gg, 256, 0, stream>>>(Ac, Bc, Wh, Keff);
    sd_kernel<<<NODES * HEADS / 4, 256, 0, stream>>>(Wh, a1s, a1d, sbuf, dbuf);
    attn_kernel<1><<<NODES, 512, 0, stream>>>(nbr_cnt, nbr, sbuf, dbuf, Wh, out, Ac);
  }
  // ---- layer 2 (K=512, Keff=1536) ----
  {
    const int K = 512, Keff = 3 * K;
    convW_kernel<<<(HEADS * 64 * (K / 8) + 255) / 256, 256, 0, stream>>>(W2, Bc, K);
    gemm_mfma<<<gg, 256, 0, stream>>>(Ac, Bc, Wh, Keff);
    sd_kernel<<<NODES * HEADS / 4, 256, 0, stream>>>(Wh, a2s, a2d, sbuf, dbuf);
    attn_kernel<1><<<NODES, 512, 0, stream>>>(nbr_cnt, nbr, sbuf, dbuf, Wh, h2, Ac);
  }
  // ---- layer 3 (K=512, Keff=1536) ----
  {
    const int K = 512, Keff = 3 * K;
    convW_kernel<<<(HEADS * 64 * (K / 8) + 255) / 256, 256, 0, stream>>>(W3, Bc, K);
    gemm_mfma<<<gg, 256, 0, stream>>>(Ac, Bc, Wh, Keff);
    sd_kernel<<<NODES * HEADS / 4, 256, 0, stream>>>(Wh, a3s, a3d, sbuf, dbuf);
    attn_kernel<0><<<NODES, 512, 0, stream>>>(nbr_cnt, nbr, sbuf, dbuf, Wh, out, Ac);
  }
}

// Round 5
// 193.842 us; speedup vs baseline: 1.8774x; 1.1147x over previous
//
#include <hip/hip_runtime.h>
#include <hip/hip_bf16.h>
#include <math.h>

// GAT, 3 layers, N=4096, H=8, O=64, F_in=256 then 512.
// Sparse softmax over ~1%-dense adj (+self loops) is EXACT vs masked dense.
//
// R2: GEMM on MFMA via exact fp16 hi/lo split (A*B = Ah*Bh + Al*Bh + Ah*Bl,
//     one fp16 GEMM with Keff=3K; B transposed so both frags are b128 reads).
// R3: build_nbr float4-vectorized; convA fused into attn epilogue (layers 2,3).
// R4: attn gather unrolled x2 (2 loads in flight, latency-bound fix);
//     dead fp32 out-store skipped for layers 1-2; s/d fused into gemm
//     epilogue (sd_kernel deleted).

#define NODES 4096
#define HEADS 8
#define HID   64
#define FOUT  512   // HEADS*HID
#define MAXNBR 128

typedef _Float16 half8 __attribute__((ext_vector_type(8)));
typedef _Float16 half4 __attribute__((ext_vector_type(4)));
typedef float f32x4 __attribute__((ext_vector_type(4)));

// ---------------------------------------------------------------------------
// Neighbor lists. One wave per row, float4 per lane (256 cols/iter).
// ---------------------------------------------------------------------------
__global__ __launch_bounds__(256) void build_nbr_kernel(
    const float* __restrict__ adj, int* __restrict__ nbr_cnt,
    int* __restrict__ nbr) {
  int wave = (blockIdx.x * blockDim.x + threadIdx.x) >> 6;
  int lane = threadIdx.x & 63;
  if (wave >= NODES) return;
  const float4* arow = (const float4*)(adj + (size_t)wave * NODES);
  int* lst = nbr + (size_t)wave * MAXNBR;
  int base = 0;
  float4 a = arow[lane];
#pragma unroll 4
  for (int it = 0; it < 16; ++it) {
    float4 cur = a;
    if (it + 1 < 16) a = arow[(it + 1) * 64 + lane];
    const int colbase = it * 256 + lane * 4;
#pragma unroll
    for (int c = 0; c < 4; ++c) {
      float v = (c == 0) ? cur.x : (c == 1) ? cur.y : (c == 2) ? cur.z : cur.w;
      unsigned long long mask = __ballot(v > 0.0f);
      if (v > 0.0f) {
        int pos = base + __popcll(mask & ((1ull << lane) - 1ull));
        if (pos < MAXNBR) lst[pos] = colbase + c;
      }
      base += __popcll(mask);
    }
  }
  if (lane == 0) nbr_cnt[wave] = base < MAXNBR ? base : MAXNBR;
}

// ---------------------------------------------------------------------------
// A [4096][K] fp32 -> Ac [4096][3K] fp16 = [Ah | Al | Ah]   (layer 1 only)
// ---------------------------------------------------------------------------
__global__ __launch_bounds__(256) void convA_kernel(
    const float* __restrict__ in, _Float16* __restrict__ out, int K) {
  int perRow = K >> 2;
  int id = blockIdx.x * blockDim.x + threadIdx.x;
  if (id >= NODES * perRow) return;
  int m = id / perRow, c = (id - m * perRow) * 4;
  float4 v = *(const float4*)(in + (size_t)m * K + c);
  half4 hi, lo;
  hi[0] = (_Float16)v.x; lo[0] = (_Float16)(v.x - (float)hi[0]);
  hi[1] = (_Float16)v.y; lo[1] = (_Float16)(v.y - (float)hi[1]);
  hi[2] = (_Float16)v.z; lo[2] = (_Float16)(v.z - (float)hi[2]);
  hi[3] = (_Float16)v.w; lo[3] = (_Float16)(v.w - (float)hi[3]);
  _Float16* rb = out + (size_t)m * 3 * K;
  *(half4*)(rb + c)         = hi;
  *(half4*)(rb + K + c)     = lo;
  *(half4*)(rb + 2 * K + c) = hi;
}

// ---------------------------------------------------------------------------
// W [8][K][64] fp32 -> Bc [512][3K] fp16, row = h*64+n, sections [Bh|Bh|Bl]
// ---------------------------------------------------------------------------
__global__ __launch_bounds__(256) void convW_kernel(
    const float* __restrict__ W, _Float16* __restrict__ Bc, int K) {
  int id = blockIdx.x * blockDim.x + threadIdx.x;
  int total = HEADS * 64 * (K >> 3);
  if (id >= total) return;
  int n = id & 63;
  int r = id >> 6;
  int kchunks = K >> 3;
  int kc = r % kchunks, h = r / kchunks;
  int k0 = kc * 8;
  half8 hi, lo;
#pragma unroll
  for (int i = 0; i < 8; ++i) {
    float w = W[((size_t)h * K + k0 + i) * 64 + n];
    _Float16 wh = (_Float16)w;
    hi[i] = wh;
    lo[i] = (_Float16)(w - (float)wh);
  }
  _Float16* rb = Bc + (size_t)(h * 64 + n) * (3 * K);
  *(half8*)(rb + k0)         = hi;
  *(half8*)(rb + K + k0)     = hi;
  *(half8*)(rb + 2 * K + k0) = lo;
}

// ---------------------------------------------------------------------------
// C[4096,512] = Ac[4096,Keff] * Bc[512,Keff]^T   (fp16 in, fp32 out)
// 64x64 tile, BK=32, 4 waves, 2x2 frags of 16x16x32 MFMA each.
// Fused epilogue: s[h,m] = C_row . a_src[h], d likewise (sd_kernel deleted).
// ---------------------------------------------------------------------------
__global__ __launch_bounds__(256) void gemm_mfma(
    const _Float16* __restrict__ A,   // [4096][Keff]
    const _Float16* __restrict__ B,   // [512][Keff]  (n-major)
    float* __restrict__ C,            // [4096][512]
    const float* __restrict__ a_src,  // [8][64]
    const float* __restrict__ a_dst,  // [8][64]
    float* __restrict__ sbuf,         // [8][4096]
    float* __restrict__ dbuf,         // [8][4096]
    int Keff) {
  __shared__ _Float16 As[64 * 40];
  __shared__ _Float16 Bs[64 * 40];
  __shared__ float sS[2][64];
  __shared__ float sD[2][64];

  const int t    = threadIdx.x;
  const int m0   = blockIdx.y * 64;
  const int n0   = blockIdx.x * 64;
  const int h    = blockIdx.x;
  const int w    = t >> 6;
  const int lane = t & 63;
  const int wr   = (w >> 1) * 32;
  const int wc   = (w & 1) * 32;
  const int lr   = lane & 15;
  const int lk   = (lane >> 4) * 8;

  const int sr = t >> 2;
  const int sc = (t & 3) * 8;
  const _Float16* gA = A + (size_t)(m0 + sr) * Keff + sc;
  const _Float16* gB = B + (size_t)(n0 + sr) * Keff + sc;

  f32x4 acc00 = {}, acc01 = {}, acc10 = {}, acc11 = {};

  half8 av = *(const half8*)(gA);
  half8 bv = *(const half8*)(gB);

  for (int k0 = 0; k0 < Keff; k0 += 32) {
    __syncthreads();
    *(half8*)(&As[sr * 40 + sc]) = av;
    *(half8*)(&Bs[sr * 40 + sc]) = bv;
    __syncthreads();
    if (k0 + 32 < Keff) {
      av = *(const half8*)(gA + k0 + 32);
      bv = *(const half8*)(gB + k0 + 32);
    }
    half8 a0 = *(const half8*)(&As[(wr + lr) * 40 + lk]);
    half8 a1 = *(const half8*)(&As[(wr + 16 + lr) * 40 + lk]);
    half8 b0 = *(const half8*)(&Bs[(wc + lr) * 40 + lk]);
    half8 b1 = *(const half8*)(&Bs[(wc + 16 + lr) * 40 + lk]);
    acc00 = __builtin_amdgcn_mfma_f32_16x16x32_f16(a0, b0, acc00, 0, 0, 0);
    acc01 = __builtin_amdgcn_mfma_f32_16x16x32_f16(a0, b1, acc01, 0, 0, 0);
    acc10 = __builtin_amdgcn_mfma_f32_16x16x32_f16(a1, b0, acc10, 0, 0, 0);
    acc11 = __builtin_amdgcn_mfma_f32_16x16x32_f16(a1, b1, acc11, 0, 0, 0);
  }

  // C/D layout: col = lane&15, row = (lane>>4)*4 + reg  [m89/m91 verified]
  const int cm = (lane >> 4) * 4;
#pragma unroll
  for (int j = 0; j < 4; ++j) {
    int m = m0 + wr + cm + j;
    C[(size_t)m * FOUT + n0 + wc + lr]      = acc00[j];
    C[(size_t)m * FOUT + n0 + wc + 16 + lr] = acc01[j];
    int m2 = m + 16;
    C[(size_t)m2 * FOUT + n0 + wc + lr]      = acc10[j];
    C[(size_t)m2 * FOUT + n0 + wc + 16 + lr] = acc11[j];
  }

  // fused s/d epilogue
  const float as0 = a_src[(h << 6) + wc + lr];
  const float as1 = a_src[(h << 6) + wc + 16 + lr];
  const float ad0 = a_dst[(h << 6) + wc + lr];
  const float ad1 = a_dst[(h << 6) + wc + 16 + lr];
  float ps[8], pd[8];
#pragma unroll
  for (int j = 0; j < 4; ++j) {
    ps[j]     = acc00[j] * as0 + acc01[j] * as1;
    ps[4 + j] = acc10[j] * as0 + acc11[j] * as1;
    pd[j]     = acc00[j] * ad0 + acc01[j] * ad1;
    pd[4 + j] = acc10[j] * ad0 + acc11[j] * ad1;
  }
#pragma unroll
  for (int off = 1; off < 16; off <<= 1) {
#pragma unroll
    for (int j = 0; j < 8; ++j) {
      ps[j] += __shfl_xor(ps[j], off);
      pd[j] += __shfl_xor(pd[j], off);
    }
  }
  if (lr == 0) {
#pragma unroll
    for (int j = 0; j < 4; ++j) {
      sS[w & 1][wr + cm + j]      = ps[j];
      sS[w & 1][wr + 16 + cm + j] = ps[4 + j];
      sD[w & 1][wr + cm + j]      = pd[j];
      sD[w & 1][wr + 16 + cm + j] = pd[4 + j];
    }
  }
  __syncthreads();
  if (t < 64) {
    sbuf[(size_t)h * NODES + m0 + t] = sS[0][t] + sS[1][t];
    dbuf[(size_t)h * NODES + m0 + t] = sD[0][t] + sD[1][t];
  }
}

// ---------------------------------------------------------------------------
// Sparse masked softmax + PV + ELU. WRITE_AC: emit next layer's fp16 hi/lo
// split A instead of the (dead) fp32 out row. Gather unrolled x2: two
// independent float4 load+FMA chains per iteration.
// ---------------------------------------------------------------------------
template <int WRITE_AC>
__global__ __launch_bounds__(512) void attn_kernel(
    const int* __restrict__ nbr_cnt, const int* __restrict__ nbr,
    const float* __restrict__ s, const float* __restrict__ d,
    const float* __restrict__ Wh, float* __restrict__ out,
    _Float16* __restrict__ Ac) {   // [4096][3*512] when WRITE_AC
  __shared__ int   lst_lds[MAXNBR];
  __shared__ float w_lds[HEADS][MAXNBR];

  const int i    = blockIdx.x;
  const int tid  = threadIdx.x;
  const int h    = tid >> 6;
  const int lane = tid & 63;
  const int cnt  = nbr_cnt[i];

  if (tid < MAXNBR)
    lst_lds[tid] = (tid < cnt) ? nbr[(size_t)i * MAXNBR + tid] : i;
  __syncthreads();

  const float s_i = s[(size_t)h * NODES + i];
  const float* dh = d + (size_t)h * NODES;
  float e0 = -1e30f, e1 = -1e30f;
  if (lane < cnt) {
    float e = s_i + dh[lst_lds[lane]];
    e0 = (e >= 0.0f) ? e : 0.2f * e;
  }
  if (lane + 64 < cnt) {
    float e = s_i + dh[lst_lds[lane + 64]];
    e1 = (e >= 0.0f) ? e : 0.2f * e;
  }
  float m = fmaxf(e0, e1);
#pragma unroll
  for (int off = 32; off; off >>= 1) m = fmaxf(m, __shfl_xor(m, off));
  float w0 = (lane < cnt) ? __expf(e0 - m) : 0.0f;
  float w1 = (lane + 64 < cnt) ? __expf(e1 - m) : 0.0f;
  w_lds[h][lane]      = w0;
  w_lds[h][lane + 64] = w1;
  float den = w0 + w1;
#pragma unroll
  for (int off = 32; off; off >>= 1) den += __shfl_xor(den, off);
  const float rden = 1.0f / den;
  __syncthreads();

  const int g  = lane >> 4;
  const int dq = (lane & 15) * 4;
  const int cnt8 = (cnt + 7) & ~7;
  float aAx = 0.f, aAy = 0.f, aAz = 0.f, aAw = 0.f;
  float aBx = 0.f, aBy = 0.f, aBz = 0.f, aBw = 0.f;
  for (int t0 = 0; t0 < cnt8; t0 += 8) {
    const int ta = t0 + g;
    const int tb = t0 + 4 + g;
    const int ja = lst_lds[ta];
    const int jb = lst_lds[tb];
    const float wa = w_lds[h][ta];
    const float wb = w_lds[h][tb];
    const float4 va = *(const float4*)(Wh + (size_t)ja * FOUT + h * HID + dq);
    const float4 vb = *(const float4*)(Wh + (size_t)jb * FOUT + h * HID + dq);
    aAx += wa * va.x; aAy += wa * va.y; aAz += wa * va.z; aAw += wa * va.w;
    aBx += wb * vb.x; aBy += wb * vb.y; aBz += wb * vb.z; aBw += wb * vb.w;
  }
  float ax = aAx + aBx, ay = aAy + aBy, az = aAz + aBz, aw = aAw + aBw;
  ax += __shfl_xor(ax, 16); ax += __shfl_xor(ax, 32);
  ay += __shfl_xor(ay, 16); ay += __shfl_xor(ay, 32);
  az += __shfl_xor(az, 16); az += __shfl_xor(az, 32);
  aw += __shfl_xor(aw, 16); aw += __shfl_xor(aw, 32);

  if (lane < 16) {
    float4 o;
    o.x = ax * rden; o.y = ay * rden; o.z = az * rden; o.w = aw * rden;
    o.x = (o.x > 0.0f) ? o.x : (__expf(o.x) - 1.0f);
    o.y = (o.y > 0.0f) ? o.y : (__expf(o.y) - 1.0f);
    o.z = (o.z > 0.0f) ? o.z : (__expf(o.z) - 1.0f);
    o.w = (o.w > 0.0f) ? o.w : (__expf(o.w) - 1.0f);
    if (WRITE_AC) {
      const int K = FOUT;  // next layer K = 512
      half4 hi, lo;
      hi[0] = (_Float16)o.x; lo[0] = (_Float16)(o.x - (float)hi[0]);
      hi[1] = (_Float16)o.y; lo[1] = (_Float16)(o.y - (float)hi[1]);
      hi[2] = (_Float16)o.z; lo[2] = (_Float16)(o.z - (float)hi[2]);
      hi[3] = (_Float16)o.w; lo[3] = (_Float16)(o.w - (float)hi[3]);
      _Float16* rb = Ac + (size_t)i * 3 * K + h * HID + dq;
      *(half4*)(rb)         = hi;
      *(half4*)(rb + K)     = lo;
      *(half4*)(rb + 2 * K) = hi;
    } else {
      *(float4*)(out + (size_t)i * FOUT + h * HID + dq) = o;
    }
  }
}

// ---------------------------------------------------------------------------
extern "C" void kernel_launch(void* const* d_in, const int* in_sizes, int n_in,
                              void* d_out, int out_size, void* d_ws,
                              size_t ws_size, hipStream_t stream) {
  const float* features = (const float*)d_in[0];
  const float* adj      = (const float*)d_in[1];
  const float* W1  = (const float*)d_in[2];
  const float* a1s = (const float*)d_in[3];
  const float* a1d = (const float*)d_in[4];
  const float* W2  = (const float*)d_in[5];
  const float* a2s = (const float*)d_in[6];
  const float* a2d = (const float*)d_in[7];
  const float* W3  = (const float*)d_in[8];
  const float* a3s = (const float*)d_in[9];
  const float* a3d = (const float*)d_in[10];
  float* out = (float*)d_out;

  char* ws = (char*)d_ws;
  size_t off = 0;
  int* nbr_cnt = (int*)(ws + off); off += (size_t)NODES * 4;
  int* nbr     = (int*)(ws + off); off += (size_t)NODES * MAXNBR * 4;
  float* Wh    = (float*)(ws + off); off += (size_t)NODES * FOUT * 4;
  float* sbuf  = (float*)(ws + off); off += (size_t)HEADS * NODES * 4;
  float* dbuf  = (float*)(ws + off); off += (size_t)HEADS * NODES * 4;
  _Float16* Ac = (_Float16*)(ws + off); off += (size_t)NODES * 3 * 512 * 2;
  _Float16* Bc = (_Float16*)(ws + off); off += (size_t)FOUT * 3 * 512 * 2;

  build_nbr_kernel<<<NODES / 4, 256, 0, stream>>>(adj, nbr_cnt, nbr);

  dim3 gg(HEADS, NODES / 64);

  // ---- layer 1 (K=256, Keff=768) ----
  {
    const int K = 256, Keff = 3 * K;
    convA_kernel<<<(NODES * (K / 4) + 255) / 256, 256, 0, stream>>>(features, Ac, K);
    convW_kernel<<<(HEADS * 64 * (K / 8) + 255) / 256, 256, 0, stream>>>(W1, Bc, K);
    gemm_mfma<<<gg, 256, 0, stream>>>(Ac, Bc, Wh, a1s, a1d, sbuf, dbuf, Keff);
    attn_kernel<1><<<NODES, 512, 0, stream>>>(nbr_cnt, nbr, sbuf, dbuf, Wh, out, Ac);
  }
  // ---- layer 2 (K=512, Keff=1536) ----
  {
    const int K = 512, Keff = 3 * K;
    convW_kernel<<<(HEADS * 64 * (K / 8) + 255) / 256, 256, 0, stream>>>(W2, Bc, K);
    gemm_mfma<<<gg, 256, 0, stream>>>(Ac, Bc, Wh, a2s, a2d, sbuf, dbuf, Keff);
    attn_kernel<1><<<NODES, 512, 0, stream>>>(nbr_cnt, nbr, sbuf, dbuf, Wh, out, Ac);
  }
  // ---- layer 3 (K=512, Keff=1536) ----
  {
    const int K = 512, Keff = 3 * K;
    convW_kernel<<<(HEADS * 64 * (K / 8) + 255) / 256, 256, 0, stream>>>(W3, Bc, K);
    gemm_mfma<<<gg, 256, 0, stream>>>(Ac, Bc, Wh, a3s, a3d, sbuf, dbuf, Keff);
    attn_kernel<0><<<NODES, 512, 0, stream>>>(nbr_cnt, nbr, sbuf, dbuf, Wh, out, Ac);
  }
}

// Round 6
// 183.803 us; speedup vs baseline: 1.9799x; 1.0546x over previous
//
#include <hip/hip_runtime.h>
#include <hip/hip_bf16.h>
#include <math.h>

// GAT, 3 layers, N=4096, H=8, O=64, F_in=256 then 512.
// Sparse softmax over ~1%-dense adj (+self loops) is EXACT vs masked dense.
//
// R2: GEMM on MFMA via exact fp16 hi/lo split (A*B = Ah*Bh + Al*Bh + Ah*Bl).
// R3: build_nbr float4-vectorized; convA fused into attn epilogue (L2,L3).
// R4: attn gather unrolled x2; dead out-store removed; s/d fused into gemm.
// R5: gather unrolled x4 (4 loads in flight); build_nbr + convA + 3x convW
//     fused into one grid-partitioned prep_kernel (10 -> 7 dispatches).

#define NODES 4096
#define HEADS 8
#define HID   64
#define FOUT  512   // HEADS*HID
#define MAXNBR 128

typedef _Float16 half8 __attribute__((ext_vector_type(8)));
typedef _Float16 half4 __attribute__((ext_vector_type(4)));
typedef float f32x4 __attribute__((ext_vector_type(4)));

// ---------------------------------------------------------------------------
// device helpers for the fused prep kernel
// ---------------------------------------------------------------------------
__device__ inline void conv_a_elem(const float* __restrict__ in,
                                   _Float16* __restrict__ out, int K, int id) {
  // id in [0, NODES*K/4)
  int perRow = K >> 2;
  int m = id / perRow, c = (id - m * perRow) * 4;
  float4 v = *(const float4*)(in + (size_t)m * K + c);
  half4 hi, lo;
  hi[0] = (_Float16)v.x; lo[0] = (_Float16)(v.x - (float)hi[0]);
  hi[1] = (_Float16)v.y; lo[1] = (_Float16)(v.y - (float)hi[1]);
  hi[2] = (_Float16)v.z; lo[2] = (_Float16)(v.z - (float)hi[2]);
  hi[3] = (_Float16)v.w; lo[3] = (_Float16)(v.w - (float)hi[3]);
  _Float16* rb = out + (size_t)m * 3 * K;
  *(half4*)(rb + c)         = hi;
  *(half4*)(rb + K + c)     = lo;
  *(half4*)(rb + 2 * K + c) = hi;
}

__device__ inline void conv_w_elem(const float* __restrict__ W,
                                   _Float16* __restrict__ Bc, int K, int id) {
  // id in [0, HEADS*64*K/8)
  int n = id & 63;
  int r = id >> 6;
  int kchunks = K >> 3;
  int kc = r % kchunks, h = r / kchunks;
  int k0 = kc * 8;
  half8 hi, lo;
#pragma unroll
  for (int i = 0; i < 8; ++i) {
    float w = W[((size_t)h * K + k0 + i) * 64 + n];
    _Float16 wh = (_Float16)w;
    hi[i] = wh;
    lo[i] = (_Float16)(w - (float)wh);
  }
  _Float16* rb = Bc + (size_t)(h * 64 + n) * (3 * K);
  *(half8*)(rb + k0)         = hi;
  *(half8*)(rb + K + k0)     = hi;
  *(half8*)(rb + 2 * K + k0) = lo;
}

// ---------------------------------------------------------------------------
// Fused prep: block-range partitioned.
//   [0,1024)      build_nbr (wave per row)
//   [1024,2048)   convA(features, K=256)
//   [2048,2112)   convW(W1, K=256)
//   [2112,2240)   convW(W2, K=512)
//   [2240,2368)   convW(W3, K=512)
// ---------------------------------------------------------------------------
__global__ __launch_bounds__(256) void prep_kernel(
    const float* __restrict__ adj, int* __restrict__ nbr_cnt,
    int* __restrict__ nbr, const float* __restrict__ features,
    _Float16* __restrict__ Ac,
    const float* __restrict__ W1, const float* __restrict__ W2,
    const float* __restrict__ W3, _Float16* __restrict__ Bc1,
    _Float16* __restrict__ Bc2, _Float16* __restrict__ Bc3) {
  const int b = blockIdx.x;
  if (b < 1024) {
    // ---- build_nbr: one wave per row, float4 per lane ----
    int wave = b * 4 + (threadIdx.x >> 6);
    int lane = threadIdx.x & 63;
    const float4* arow = (const float4*)(adj + (size_t)wave * NODES);
    int* lst = nbr + (size_t)wave * MAXNBR;
    int base = 0;
    float4 a = arow[lane];
#pragma unroll 4
    for (int it = 0; it < 16; ++it) {
      float4 cur = a;
      if (it + 1 < 16) a = arow[(it + 1) * 64 + lane];
      const int colbase = it * 256 + lane * 4;
#pragma unroll
      for (int c = 0; c < 4; ++c) {
        float v = (c == 0) ? cur.x : (c == 1) ? cur.y : (c == 2) ? cur.z : cur.w;
        unsigned long long mask = __ballot(v > 0.0f);
        if (v > 0.0f) {
          int pos = base + __popcll(mask & ((1ull << lane) - 1ull));
          if (pos < MAXNBR) lst[pos] = colbase + c;
        }
        base += __popcll(mask);
      }
    }
    if (lane == 0) nbr_cnt[wave] = base < MAXNBR ? base : MAXNBR;
  } else if (b < 2048) {
    conv_a_elem(features, Ac, 256, (b - 1024) * 256 + threadIdx.x);
  } else if (b < 2112) {
    conv_w_elem(W1, Bc1, 256, (b - 2048) * 256 + threadIdx.x);
  } else if (b < 2240) {
    conv_w_elem(W2, Bc2, 512, (b - 2112) * 256 + threadIdx.x);
  } else {
    conv_w_elem(W3, Bc3, 512, (b - 2240) * 256 + threadIdx.x);
  }
}

// ---------------------------------------------------------------------------
// C[4096,512] = Ac[4096,Keff] * Bc[512,Keff]^T   (fp16 in, fp32 out)
// 64x64 tile, BK=32, 4 waves, 2x2 frags of 16x16x32 MFMA each.
// Fused epilogue: s[h,m] = C_row . a_src[h], d likewise.
// ---------------------------------------------------------------------------
__global__ __launch_bounds__(256) void gemm_mfma(
    const _Float16* __restrict__ A,   // [4096][Keff]
    const _Float16* __restrict__ B,   // [512][Keff]  (n-major)
    float* __restrict__ C,            // [4096][512]
    const float* __restrict__ a_src,  // [8][64]
    const float* __restrict__ a_dst,  // [8][64]
    float* __restrict__ sbuf,         // [8][4096]
    float* __restrict__ dbuf,         // [8][4096]
    int Keff) {
  __shared__ _Float16 As[64 * 40];
  __shared__ _Float16 Bs[64 * 40];
  __shared__ float sS[2][64];
  __shared__ float sD[2][64];

  const int t    = threadIdx.x;
  const int m0   = blockIdx.y * 64;
  const int n0   = blockIdx.x * 64;
  const int h    = blockIdx.x;
  const int w    = t >> 6;
  const int lane = t & 63;
  const int wr   = (w >> 1) * 32;
  const int wc   = (w & 1) * 32;
  const int lr   = lane & 15;
  const int lk   = (lane >> 4) * 8;

  const int sr = t >> 2;
  const int sc = (t & 3) * 8;
  const _Float16* gA = A + (size_t)(m0 + sr) * Keff + sc;
  const _Float16* gB = B + (size_t)(n0 + sr) * Keff + sc;

  f32x4 acc00 = {}, acc01 = {}, acc10 = {}, acc11 = {};

  half8 av = *(const half8*)(gA);
  half8 bv = *(const half8*)(gB);

  for (int k0 = 0; k0 < Keff; k0 += 32) {
    __syncthreads();
    *(half8*)(&As[sr * 40 + sc]) = av;
    *(half8*)(&Bs[sr * 40 + sc]) = bv;
    __syncthreads();
    if (k0 + 32 < Keff) {
      av = *(const half8*)(gA + k0 + 32);
      bv = *(const half8*)(gB + k0 + 32);
    }
    half8 a0 = *(const half8*)(&As[(wr + lr) * 40 + lk]);
    half8 a1 = *(const half8*)(&As[(wr + 16 + lr) * 40 + lk]);
    half8 b0 = *(const half8*)(&Bs[(wc + lr) * 40 + lk]);
    half8 b1 = *(const half8*)(&Bs[(wc + 16 + lr) * 40 + lk]);
    acc00 = __builtin_amdgcn_mfma_f32_16x16x32_f16(a0, b0, acc00, 0, 0, 0);
    acc01 = __builtin_amdgcn_mfma_f32_16x16x32_f16(a0, b1, acc01, 0, 0, 0);
    acc10 = __builtin_amdgcn_mfma_f32_16x16x32_f16(a1, b0, acc10, 0, 0, 0);
    acc11 = __builtin_amdgcn_mfma_f32_16x16x32_f16(a1, b1, acc11, 0, 0, 0);
  }

  // C/D layout: col = lane&15, row = (lane>>4)*4 + reg  [m89/m91 verified]
  const int cm = (lane >> 4) * 4;
#pragma unroll
  for (int j = 0; j < 4; ++j) {
    int m = m0 + wr + cm + j;
    C[(size_t)m * FOUT + n0 + wc + lr]      = acc00[j];
    C[(size_t)m * FOUT + n0 + wc + 16 + lr] = acc01[j];
    int m2 = m + 16;
    C[(size_t)m2 * FOUT + n0 + wc + lr]      = acc10[j];
    C[(size_t)m2 * FOUT + n0 + wc + 16 + lr] = acc11[j];
  }

  // fused s/d epilogue
  const float as0 = a_src[(h << 6) + wc + lr];
  const float as1 = a_src[(h << 6) + wc + 16 + lr];
  const float ad0 = a_dst[(h << 6) + wc + lr];
  const float ad1 = a_dst[(h << 6) + wc + 16 + lr];
  float ps[8], pd[8];
#pragma unroll
  for (int j = 0; j < 4; ++j) {
    ps[j]     = acc00[j] * as0 + acc01[j] * as1;
    ps[4 + j] = acc10[j] * as0 + acc11[j] * as1;
    pd[j]     = acc00[j] * ad0 + acc01[j] * ad1;
    pd[4 + j] = acc10[j] * ad0 + acc11[j] * ad1;
  }
#pragma unroll
  for (int off = 1; off < 16; off <<= 1) {
#pragma unroll
    for (int j = 0; j < 8; ++j) {
      ps[j] += __shfl_xor(ps[j], off);
      pd[j] += __shfl_xor(pd[j], off);
    }
  }
  if (lr == 0) {
#pragma unroll
    for (int j = 0; j < 4; ++j) {
      sS[w & 1][wr + cm + j]      = ps[j];
      sS[w & 1][wr + 16 + cm + j] = ps[4 + j];
      sD[w & 1][wr + cm + j]      = pd[j];
      sD[w & 1][wr + 16 + cm + j] = pd[4 + j];
    }
  }
  __syncthreads();
  if (t < 64) {
    sbuf[(size_t)h * NODES + m0 + t] = sS[0][t] + sS[1][t];
    dbuf[(size_t)h * NODES + m0 + t] = sD[0][t] + sD[1][t];
  }
}

// ---------------------------------------------------------------------------
// Sparse masked softmax + PV + ELU. WRITE_AC: emit next layer's fp16 hi/lo
// split A instead of the (dead) fp32 out row. Gather unrolled x4.
// ---------------------------------------------------------------------------
template <int WRITE_AC>
__global__ __launch_bounds__(512) void attn_kernel(
    const int* __restrict__ nbr_cnt, const int* __restrict__ nbr,
    const float* __restrict__ s, const float* __restrict__ d,
    const float* __restrict__ Wh, float* __restrict__ out,
    _Float16* __restrict__ Ac) {   // [4096][3*512] when WRITE_AC
  __shared__ int   lst_lds[MAXNBR];
  __shared__ float w_lds[HEADS][MAXNBR];

  const int i    = blockIdx.x;
  const int tid  = threadIdx.x;
  const int h    = tid >> 6;
  const int lane = tid & 63;
  const int cnt  = nbr_cnt[i];

  if (tid < MAXNBR)
    lst_lds[tid] = (tid < cnt) ? nbr[(size_t)i * MAXNBR + tid] : i;
  __syncthreads();

  const float s_i = s[(size_t)h * NODES + i];
  const float* dh = d + (size_t)h * NODES;
  float e0 = -1e30f, e1 = -1e30f;
  if (lane < cnt) {
    float e = s_i + dh[lst_lds[lane]];
    e0 = (e >= 0.0f) ? e : 0.2f * e;
  }
  if (lane + 64 < cnt) {
    float e = s_i + dh[lst_lds[lane + 64]];
    e1 = (e >= 0.0f) ? e : 0.2f * e;
  }
  float m = fmaxf(e0, e1);
#pragma unroll
  for (int off = 32; off; off >>= 1) m = fmaxf(m, __shfl_xor(m, off));
  float w0 = (lane < cnt) ? __expf(e0 - m) : 0.0f;
  float w1 = (lane + 64 < cnt) ? __expf(e1 - m) : 0.0f;
  w_lds[h][lane]      = w0;
  w_lds[h][lane + 64] = w1;
  float den = w0 + w1;
#pragma unroll
  for (int off = 32; off; off >>= 1) den += __shfl_xor(den, off);
  const float rden = 1.0f / den;
  __syncthreads();

  // gather: 16 neighbors per iteration across 4 independent chains.
  const int g  = lane >> 4;
  const int dq = (lane & 15) * 4;
  const int cnt16 = (cnt + 15) & ~15;
  float aAx = 0.f, aAy = 0.f, aAz = 0.f, aAw = 0.f;
  float aBx = 0.f, aBy = 0.f, aBz = 0.f, aBw = 0.f;
  float aCx = 0.f, aCy = 0.f, aCz = 0.f, aCw = 0.f;
  float aDx = 0.f, aDy = 0.f, aDz = 0.f, aDw = 0.f;
  for (int t0 = 0; t0 < cnt16; t0 += 16) {
    const int ta = t0 + g;
    const int tb = ta + 4;
    const int tc = ta + 8;
    const int td = ta + 12;
    const int ja = lst_lds[ta], jb = lst_lds[tb];
    const int jc = lst_lds[tc], jd = lst_lds[td];
    const float wa = w_lds[h][ta], wb = w_lds[h][tb];
    const float wc = w_lds[h][tc], wd = w_lds[h][td];
    const float4 va = *(const float4*)(Wh + (size_t)ja * FOUT + h * HID + dq);
    const float4 vb = *(const float4*)(Wh + (size_t)jb * FOUT + h * HID + dq);
    const float4 vc = *(const float4*)(Wh + (size_t)jc * FOUT + h * HID + dq);
    const float4 vd = *(const float4*)(Wh + (size_t)jd * FOUT + h * HID + dq);
    aAx += wa * va.x; aAy += wa * va.y; aAz += wa * va.z; aAw += wa * va.w;
    aBx += wb * vb.x; aBy += wb * vb.y; aBz += wb * vb.z; aBw += wb * vb.w;
    aCx += wc * vc.x; aCy += wc * vc.y; aCz += wc * vc.z; aCw += wc * vc.w;
    aDx += wd * vd.x; aDy += wd * vd.y; aDz += wd * vd.z; aDw += wd * vd.w;
  }
  float ax = (aAx + aBx) + (aCx + aDx);
  float ay = (aAy + aBy) + (aCy + aDy);
  float az = (aAz + aBz) + (aCz + aDz);
  float aw = (aAw + aBw) + (aCw + aDw);
  ax += __shfl_xor(ax, 16); ax += __shfl_xor(ax, 32);
  ay += __shfl_xor(ay, 16); ay += __shfl_xor(ay, 32);
  az += __shfl_xor(az, 16); az += __shfl_xor(az, 32);
  aw += __shfl_xor(aw, 16); aw += __shfl_xor(aw, 32);

  if (lane < 16) {
    float4 o;
    o.x = ax * rden; o.y = ay * rden; o.z = az * rden; o.w = aw * rden;
    o.x = (o.x > 0.0f) ? o.x : (__expf(o.x) - 1.0f);
    o.y = (o.y > 0.0f) ? o.y : (__expf(o.y) - 1.0f);
    o.z = (o.z > 0.0f) ? o.z : (__expf(o.z) - 1.0f);
    o.w = (o.w > 0.0f) ? o.w : (__expf(o.w) - 1.0f);
    if (WRITE_AC) {
      const int K = FOUT;  // next layer K = 512
      half4 hi, lo;
      hi[0] = (_Float16)o.x; lo[0] = (_Float16)(o.x - (float)hi[0]);
      hi[1] = (_Float16)o.y; lo[1] = (_Float16)(o.y - (float)hi[1]);
      hi[2] = (_Float16)o.z; lo[2] = (_Float16)(o.z - (float)hi[2]);
      hi[3] = (_Float16)o.w; lo[3] = (_Float16)(o.w - (float)hi[3]);
      _Float16* rb = Ac + (size_t)i * 3 * K + h * HID + dq;
      *(half4*)(rb)         = hi;
      *(half4*)(rb + K)     = lo;
      *(half4*)(rb + 2 * K) = hi;
    } else {
      *(float4*)(out + (size_t)i * FOUT + h * HID + dq) = o;
    }
  }
}

// ---------------------------------------------------------------------------
extern "C" void kernel_launch(void* const* d_in, const int* in_sizes, int n_in,
                              void* d_out, int out_size, void* d_ws,
                              size_t ws_size, hipStream_t stream) {
  const float* features = (const float*)d_in[0];
  const float* adj      = (const float*)d_in[1];
  const float* W1  = (const float*)d_in[2];
  const float* a1s = (const float*)d_in[3];
  const float* a1d = (const float*)d_in[4];
  const float* W2  = (const float*)d_in[5];
  const float* a2s = (const float*)d_in[6];
  const float* a2d = (const float*)d_in[7];
  const float* W3  = (const float*)d_in[8];
  const float* a3s = (const float*)d_in[9];
  const float* a3d = (const float*)d_in[10];
  float* out = (float*)d_out;

  char* ws = (char*)d_ws;
  size_t off = 0;
  int* nbr_cnt = (int*)(ws + off); off += (size_t)NODES * 4;
  int* nbr     = (int*)(ws + off); off += (size_t)NODES * MAXNBR * 4;
  float* Wh    = (float*)(ws + off); off += (size_t)NODES * FOUT * 4;
  float* sbuf  = (float*)(ws + off); off += (size_t)HEADS * NODES * 4;
  float* dbuf  = (float*)(ws + off); off += (size_t)HEADS * NODES * 4;
  _Float16* Ac = (_Float16*)(ws + off); off += (size_t)NODES * 3 * 512 * 2;
  _Float16* Bc1 = (_Float16*)(ws + off); off += (size_t)FOUT * 3 * 256 * 2;
  _Float16* Bc2 = (_Float16*)(ws + off); off += (size_t)FOUT * 3 * 512 * 2;
  _Float16* Bc3 = (_Float16*)(ws + off); off += (size_t)FOUT * 3 * 512 * 2;

  prep_kernel<<<2368, 256, 0, stream>>>(adj, nbr_cnt, nbr, features, Ac,
                                        W1, W2, W3, Bc1, Bc2, Bc3);

  dim3 gg(HEADS, NODES / 64);

  // ---- layer 1 (K=256, Keff=768) ----
  gemm_mfma<<<gg, 256, 0, stream>>>(Ac, Bc1, Wh, a1s, a1d, sbuf, dbuf, 768);
  attn_kernel<1><<<NODES, 512, 0, stream>>>(nbr_cnt, nbr, sbuf, dbuf, Wh, out, Ac);
  // ---- layer 2 (K=512, Keff=1536) ----
  gemm_mfma<<<gg, 256, 0, stream>>>(Ac, Bc2, Wh, a2s, a2d, sbuf, dbuf, 1536);
  attn_kernel<1><<<NODES, 512, 0, stream>>>(nbr_cnt, nbr, sbuf, dbuf, Wh, out, Ac);
  // ---- layer 3 (K=512, Keff=1536) ----
  gemm_mfma<<<gg, 256, 0, stream>>>(Ac, Bc3, Wh, a3s, a3d, sbuf, dbuf, 1536);
  attn_kernel<0><<<NODES, 512, 0, stream>>>(nbr_cnt, nbr, sbuf, dbuf, Wh, out, Ac);
}

// Round 7
// 166.379 us; speedup vs baseline: 2.1873x; 1.1047x over previous
//
#include <hip/hip_runtime.h>
#include <hip/hip_bf16.h>
#include <math.h>

// GAT, 3 layers, N=4096, H=8, O=64, F_in=256 then 512.
// Sparse softmax over ~1%-dense adj (+self loops) is EXACT vs masked dense.
//
// R2: GEMM on MFMA via exact fp16 hi/lo split (A*B = Ah*Bh + Al*Bh + Ah*Bl).
// R3: build_nbr float4-vectorized; convA fused into attn epilogue.
// R4: attn gather unrolled; dead stores removed; s/d fused into gemm.
// R5: gather x4 chains; all prep fused into one grid-partitioned kernel.
// R6: layers 2-3 gather Wh in fp16 (halves the dominant L2-miss/L3 traffic;
//     |Wh_23| <= ~0.7 so fp16 adds <=3.4e-4/layer, layer-1 Wh stays fp32);
//     their GEMMs write 4MB fp16 Wh16 instead of the now-dead 8MB fp32 C.

#define NODES 4096
#define HEADS 8
#define HID   64
#define FOUT  512   // HEADS*HID
#define MAXNBR 128

typedef _Float16 half8 __attribute__((ext_vector_type(8)));
typedef _Float16 half4 __attribute__((ext_vector_type(4)));
typedef float f32x4 __attribute__((ext_vector_type(4)));

// ---------------------------------------------------------------------------
// device helpers for the fused prep kernel
// ---------------------------------------------------------------------------
__device__ inline void conv_a_elem(const float* __restrict__ in,
                                   _Float16* __restrict__ out, int K, int id) {
  int perRow = K >> 2;
  int m = id / perRow, c = (id - m * perRow) * 4;
  float4 v = *(const float4*)(in + (size_t)m * K + c);
  half4 hi, lo;
  hi[0] = (_Float16)v.x; lo[0] = (_Float16)(v.x - (float)hi[0]);
  hi[1] = (_Float16)v.y; lo[1] = (_Float16)(v.y - (float)hi[1]);
  hi[2] = (_Float16)v.z; lo[2] = (_Float16)(v.z - (float)hi[2]);
  hi[3] = (_Float16)v.w; lo[3] = (_Float16)(v.w - (float)hi[3]);
  _Float16* rb = out + (size_t)m * 3 * K;
  *(half4*)(rb + c)         = hi;
  *(half4*)(rb + K + c)     = lo;
  *(half4*)(rb + 2 * K + c) = hi;
}

__device__ inline void conv_w_elem(const float* __restrict__ W,
                                   _Float16* __restrict__ Bc, int K, int id) {
  int n = id & 63;
  int r = id >> 6;
  int kchunks = K >> 3;
  int kc = r % kchunks, h = r / kchunks;
  int k0 = kc * 8;
  half8 hi, lo;
#pragma unroll
  for (int i = 0; i < 8; ++i) {
    float w = W[((size_t)h * K + k0 + i) * 64 + n];
    _Float16 wh = (_Float16)w;
    hi[i] = wh;
    lo[i] = (_Float16)(w - (float)wh);
  }
  _Float16* rb = Bc + (size_t)(h * 64 + n) * (3 * K);
  *(half8*)(rb + k0)         = hi;
  *(half8*)(rb + K + k0)     = hi;
  *(half8*)(rb + 2 * K + k0) = lo;
}

// ---------------------------------------------------------------------------
// Fused prep: block-range partitioned.
// ---------------------------------------------------------------------------
__global__ __launch_bounds__(256) void prep_kernel(
    const float* __restrict__ adj, int* __restrict__ nbr_cnt,
    int* __restrict__ nbr, const float* __restrict__ features,
    _Float16* __restrict__ Ac,
    const float* __restrict__ W1, const float* __restrict__ W2,
    const float* __restrict__ W3, _Float16* __restrict__ Bc1,
    _Float16* __restrict__ Bc2, _Float16* __restrict__ Bc3) {
  const int b = blockIdx.x;
  if (b < 1024) {
    int wave = b * 4 + (threadIdx.x >> 6);
    int lane = threadIdx.x & 63;
    const float4* arow = (const float4*)(adj + (size_t)wave * NODES);
    int* lst = nbr + (size_t)wave * MAXNBR;
    int base = 0;
    float4 a = arow[lane];
#pragma unroll 4
    for (int it = 0; it < 16; ++it) {
      float4 cur = a;
      if (it + 1 < 16) a = arow[(it + 1) * 64 + lane];
      const int colbase = it * 256 + lane * 4;
#pragma unroll
      for (int c = 0; c < 4; ++c) {
        float v = (c == 0) ? cur.x : (c == 1) ? cur.y : (c == 2) ? cur.z : cur.w;
        unsigned long long mask = __ballot(v > 0.0f);
        if (v > 0.0f) {
          int pos = base + __popcll(mask & ((1ull << lane) - 1ull));
          if (pos < MAXNBR) lst[pos] = colbase + c;
        }
        base += __popcll(mask);
      }
    }
    if (lane == 0) nbr_cnt[wave] = base < MAXNBR ? base : MAXNBR;
  } else if (b < 2048) {
    conv_a_elem(features, Ac, 256, (b - 1024) * 256 + threadIdx.x);
  } else if (b < 2112) {
    conv_w_elem(W1, Bc1, 256, (b - 2048) * 256 + threadIdx.x);
  } else if (b < 2240) {
    conv_w_elem(W2, Bc2, 512, (b - 2112) * 256 + threadIdx.x);
  } else {
    conv_w_elem(W3, Bc3, 512, (b - 2240) * 256 + threadIdx.x);
  }
}

// ---------------------------------------------------------------------------
// C = Ac[4096,Keff] * Bc[512,Keff]^T. 64x64 tile, BK=32, 4 waves, 2x2 frags.
// F16OUT=0: write fp32 C.  F16OUT=1: write fp16 Wh16 (fp32 C is dead).
// Fused epilogue: s[h,m], d[h,m] from accumulators.
// ---------------------------------------------------------------------------
template <int F16OUT>
__global__ __launch_bounds__(256) void gemm_mfma(
    const _Float16* __restrict__ A,   // [4096][Keff]
    const _Float16* __restrict__ B,   // [512][Keff]  (n-major)
    float* __restrict__ C,            // [4096][512]   (F16OUT=0)
    _Float16* __restrict__ C16,       // [4096][512]   (F16OUT=1)
    const float* __restrict__ a_src,  // [8][64]
    const float* __restrict__ a_dst,  // [8][64]
    float* __restrict__ sbuf,         // [8][4096]
    float* __restrict__ dbuf,         // [8][4096]
    int Keff) {
  __shared__ _Float16 As[64 * 40];
  __shared__ _Float16 Bs[64 * 40];
  __shared__ float sS[2][64];
  __shared__ float sD[2][64];

  const int t    = threadIdx.x;
  const int m0   = blockIdx.y * 64;
  const int n0   = blockIdx.x * 64;
  const int h    = blockIdx.x;
  const int w    = t >> 6;
  const int lane = t & 63;
  const int wr   = (w >> 1) * 32;
  const int wc   = (w & 1) * 32;
  const int lr   = lane & 15;
  const int lk   = (lane >> 4) * 8;

  const int sr = t >> 2;
  const int sc = (t & 3) * 8;
  const _Float16* gA = A + (size_t)(m0 + sr) * Keff + sc;
  const _Float16* gB = B + (size_t)(n0 + sr) * Keff + sc;

  f32x4 acc00 = {}, acc01 = {}, acc10 = {}, acc11 = {};

  half8 av = *(const half8*)(gA);
  half8 bv = *(const half8*)(gB);

  for (int k0 = 0; k0 < Keff; k0 += 32) {
    __syncthreads();
    *(half8*)(&As[sr * 40 + sc]) = av;
    *(half8*)(&Bs[sr * 40 + sc]) = bv;
    __syncthreads();
    if (k0 + 32 < Keff) {
      av = *(const half8*)(gA + k0 + 32);
      bv = *(const half8*)(gB + k0 + 32);
    }
    half8 a0 = *(const half8*)(&As[(wr + lr) * 40 + lk]);
    half8 a1 = *(const half8*)(&As[(wr + 16 + lr) * 40 + lk]);
    half8 b0 = *(const half8*)(&Bs[(wc + lr) * 40 + lk]);
    half8 b1 = *(const half8*)(&Bs[(wc + 16 + lr) * 40 + lk]);
    acc00 = __builtin_amdgcn_mfma_f32_16x16x32_f16(a0, b0, acc00, 0, 0, 0);
    acc01 = __builtin_amdgcn_mfma_f32_16x16x32_f16(a0, b1, acc01, 0, 0, 0);
    acc10 = __builtin_amdgcn_mfma_f32_16x16x32_f16(a1, b0, acc10, 0, 0, 0);
    acc11 = __builtin_amdgcn_mfma_f32_16x16x32_f16(a1, b1, acc11, 0, 0, 0);
  }

  // C/D layout: col = lane&15, row = (lane>>4)*4 + reg  [m89/m91 verified]
  const int cm = (lane >> 4) * 4;
#pragma unroll
  for (int j = 0; j < 4; ++j) {
    int m  = m0 + wr + cm + j;
    int m2 = m + 16;
    if constexpr (F16OUT) {
      C16[(size_t)m * FOUT + n0 + wc + lr]       = (_Float16)acc00[j];
      C16[(size_t)m * FOUT + n0 + wc + 16 + lr]  = (_Float16)acc01[j];
      C16[(size_t)m2 * FOUT + n0 + wc + lr]      = (_Float16)acc10[j];
      C16[(size_t)m2 * FOUT + n0 + wc + 16 + lr] = (_Float16)acc11[j];
    } else {
      C[(size_t)m * FOUT + n0 + wc + lr]       = acc00[j];
      C[(size_t)m * FOUT + n0 + wc + 16 + lr]  = acc01[j];
      C[(size_t)m2 * FOUT + n0 + wc + lr]      = acc10[j];
      C[(size_t)m2 * FOUT + n0 + wc + 16 + lr] = acc11[j];
    }
  }

  // fused s/d epilogue (always fp32-exact from accumulators)
  const float as0 = a_src[(h << 6) + wc + lr];
  const float as1 = a_src[(h << 6) + wc + 16 + lr];
  const float ad0 = a_dst[(h << 6) + wc + lr];
  const float ad1 = a_dst[(h << 6) + wc + 16 + lr];
  float ps[8], pd[8];
#pragma unroll
  for (int j = 0; j < 4; ++j) {
    ps[j]     = acc00[j] * as0 + acc01[j] * as1;
    ps[4 + j] = acc10[j] * as0 + acc11[j] * as1;
    pd[j]     = acc00[j] * ad0 + acc01[j] * ad1;
    pd[4 + j] = acc10[j] * ad0 + acc11[j] * ad1;
  }
#pragma unroll
  for (int off = 1; off < 16; off <<= 1) {
#pragma unroll
    for (int j = 0; j < 8; ++j) {
      ps[j] += __shfl_xor(ps[j], off);
      pd[j] += __shfl_xor(pd[j], off);
    }
  }
  if (lr == 0) {
#pragma unroll
    for (int j = 0; j < 4; ++j) {
      sS[w & 1][wr + cm + j]      = ps[j];
      sS[w & 1][wr + 16 + cm + j] = ps[4 + j];
      sD[w & 1][wr + cm + j]      = pd[j];
      sD[w & 1][wr + 16 + cm + j] = pd[4 + j];
    }
  }
  __syncthreads();
  if (t < 64) {
    sbuf[(size_t)h * NODES + m0 + t] = sS[0][t] + sS[1][t];
    dbuf[(size_t)h * NODES + m0 + t] = sD[0][t] + sD[1][t];
  }
}

// ---------------------------------------------------------------------------
// Sparse masked softmax + PV + ELU.
// F16IN=0: gather fp32 Wh, 4x float4 chains (16 nbrs/iter).
// F16IN=1: gather fp16 Wh16, 8 subgroups x half8, 2 chains (16 nbrs/iter).
// WRITE_AC: emit next layer's fp16 hi/lo split A instead of fp32 out.
// ---------------------------------------------------------------------------
template <int WRITE_AC, int F16IN>
__global__ __launch_bounds__(512) void attn_kernel(
    const int* __restrict__ nbr_cnt, const int* __restrict__ nbr,
    const float* __restrict__ s, const float* __restrict__ d,
    const float* __restrict__ Wh, const _Float16* __restrict__ Wh16,
    float* __restrict__ out, _Float16* __restrict__ Ac) {
  __shared__ int   lst_lds[MAXNBR];
  __shared__ float w_lds[HEADS][MAXNBR];

  const int i    = blockIdx.x;
  const int tid  = threadIdx.x;
  const int h    = tid >> 6;
  const int lane = tid & 63;
  const int cnt  = nbr_cnt[i];

  if (tid < MAXNBR)
    lst_lds[tid] = (tid < cnt) ? nbr[(size_t)i * MAXNBR + tid] : i;
  __syncthreads();

  const float s_i = s[(size_t)h * NODES + i];
  const float* dh = d + (size_t)h * NODES;
  float e0 = -1e30f, e1 = -1e30f;
  if (lane < cnt) {
    float e = s_i + dh[lst_lds[lane]];
    e0 = (e >= 0.0f) ? e : 0.2f * e;
  }
  if (lane + 64 < cnt) {
    float e = s_i + dh[lst_lds[lane + 64]];
    e1 = (e >= 0.0f) ? e : 0.2f * e;
  }
  float m = fmaxf(e0, e1);
#pragma unroll
  for (int off = 32; off; off >>= 1) m = fmaxf(m, __shfl_xor(m, off));
  float w0 = (lane < cnt) ? __expf(e0 - m) : 0.0f;
  float w1 = (lane + 64 < cnt) ? __expf(e1 - m) : 0.0f;
  w_lds[h][lane]      = w0;
  w_lds[h][lane + 64] = w1;
  float den = w0 + w1;
#pragma unroll
  for (int off = 32; off; off >>= 1) den += __shfl_xor(den, off);
  const float rden = 1.0f / den;
  __syncthreads();

  if constexpr (F16IN) {
    // 8 subgroups of 8 lanes; lane covers 8 dims via half8; 2 chains.
    const int g  = lane >> 3;          // neighbor subgroup 0..7
    const int d8 = (lane & 7) * 8;     // dim octet
    const int cnt16 = (cnt + 15) & ~15;
    float aA[8] = {}, aB[8] = {};
    for (int t0 = 0; t0 < cnt16; t0 += 16) {
      const int ta = t0 + g;
      const int tb = ta + 8;
      const int ja = lst_lds[ta], jb = lst_lds[tb];
      const float wa = w_lds[h][ta], wb = w_lds[h][tb];
      const half8 va = *(const half8*)(Wh16 + (size_t)ja * FOUT + h * HID + d8);
      const half8 vb = *(const half8*)(Wh16 + (size_t)jb * FOUT + h * HID + d8);
#pragma unroll
      for (int q = 0; q < 8; ++q) {
        aA[q] += wa * (float)va[q];
        aB[q] += wb * (float)vb[q];
      }
    }
    float acc[8];
#pragma unroll
    for (int q = 0; q < 8; ++q) acc[q] = aA[q] + aB[q];
#pragma unroll
    for (int off = 8; off <= 32; off <<= 1)
#pragma unroll
      for (int q = 0; q < 8; ++q) acc[q] += __shfl_xor(acc[q], off);

    if (lane < 8) {
      float o[8];
#pragma unroll
      for (int q = 0; q < 8; ++q) {
        float v = acc[q] * rden;
        o[q] = (v > 0.0f) ? v : (__expf(v) - 1.0f);
      }
      if (WRITE_AC) {
        const int K = FOUT;
        half8 hi, lo;
#pragma unroll
        for (int q = 0; q < 8; ++q) {
          hi[q] = (_Float16)o[q];
          lo[q] = (_Float16)(o[q] - (float)hi[q]);
        }
        _Float16* rb = Ac + (size_t)i * 3 * K + h * HID + d8;
        *(half8*)(rb)         = hi;
        *(half8*)(rb + K)     = lo;
        *(half8*)(rb + 2 * K) = hi;
      } else {
        float* ob = out + (size_t)i * FOUT + h * HID + d8;
        *(float4*)(ob)     = make_float4(o[0], o[1], o[2], o[3]);
        *(float4*)(ob + 4) = make_float4(o[4], o[5], o[6], o[7]);
      }
    }
  } else {
    // fp32 gather: 4 subgroups of 16 lanes, float4, 4 chains.
    const int g  = lane >> 4;
    const int dq = (lane & 15) * 4;
    const int cnt16 = (cnt + 15) & ~15;
    float aAx = 0.f, aAy = 0.f, aAz = 0.f, aAw = 0.f;
    float aBx = 0.f, aBy = 0.f, aBz = 0.f, aBw = 0.f;
    float aCx = 0.f, aCy = 0.f, aCz = 0.f, aCw = 0.f;
    float aDx = 0.f, aDy = 0.f, aDz = 0.f, aDw = 0.f;
    for (int t0 = 0; t0 < cnt16; t0 += 16) {
      const int ta = t0 + g;
      const int tb = ta + 4;
      const int tc = ta + 8;
      const int td = ta + 12;
      const int ja = lst_lds[ta], jb = lst_lds[tb];
      const int jc = lst_lds[tc], jd = lst_lds[td];
      const float wa = w_lds[h][ta], wb = w_lds[h][tb];
      const float wc = w_lds[h][tc], wd = w_lds[h][td];
      const float4 va = *(const float4*)(Wh + (size_t)ja * FOUT + h * HID + dq);
      const float4 vb = *(const float4*)(Wh + (size_t)jb * FOUT + h * HID + dq);
      const float4 vc = *(const float4*)(Wh + (size_t)jc * FOUT + h * HID + dq);
      const float4 vd = *(const float4*)(Wh + (size_t)jd * FOUT + h * HID + dq);
      aAx += wa * va.x; aAy += wa * va.y; aAz += wa * va.z; aAw += wa * va.w;
      aBx += wb * vb.x; aBy += wb * vb.y; aBz += wb * vb.z; aBw += wb * vb.w;
      aCx += wc * vc.x; aCy += wc * vc.y; aCz += wc * vc.z; aCw += wc * vc.w;
      aDx += wd * vd.x; aDy += wd * vd.y; aDz += wd * vd.z; aDw += wd * vd.w;
    }
    float ax = (aAx + aBx) + (aCx + aDx);
    float ay = (aAy + aBy) + (aCy + aDy);
    float az = (aAz + aBz) + (aCz + aDz);
    float aw = (aAw + aBw) + (aCw + aDw);
    ax += __shfl_xor(ax, 16); ax += __shfl_xor(ax, 32);
    ay += __shfl_xor(ay, 16); ay += __shfl_xor(ay, 32);
    az += __shfl_xor(az, 16); az += __shfl_xor(az, 32);
    aw += __shfl_xor(aw, 16); aw += __shfl_xor(aw, 32);

    if (lane < 16) {
      float4 o;
      o.x = ax * rden; o.y = ay * rden; o.z = az * rden; o.w = aw * rden;
      o.x = (o.x > 0.0f) ? o.x : (__expf(o.x) - 1.0f);
      o.y = (o.y > 0.0f) ? o.y : (__expf(o.y) - 1.0f);
      o.z = (o.z > 0.0f) ? o.z : (__expf(o.z) - 1.0f);
      o.w = (o.w > 0.0f) ? o.w : (__expf(o.w) - 1.0f);
      if (WRITE_AC) {
        const int K = FOUT;
        half4 hi, lo;
        hi[0] = (_Float16)o.x; lo[0] = (_Float16)(o.x - (float)hi[0]);
        hi[1] = (_Float16)o.y; lo[1] = (_Float16)(o.y - (float)hi[1]);
        hi[2] = (_Float16)o.z; lo[2] = (_Float16)(o.z - (float)hi[2]);
        hi[3] = (_Float16)o.w; lo[3] = (_Float16)(o.w - (float)hi[3]);
        _Float16* rb = Ac + (size_t)i * 3 * K + h * HID + dq;
        *(half4*)(rb)         = hi;
        *(half4*)(rb + K)     = lo;
        *(half4*)(rb + 2 * K) = hi;
      } else {
        *(float4*)(out + (size_t)i * FOUT + h * HID + dq) = o;
      }
    }
  }
}

// ---------------------------------------------------------------------------
extern "C" void kernel_launch(void* const* d_in, const int* in_sizes, int n_in,
                              void* d_out, int out_size, void* d_ws,
                              size_t ws_size, hipStream_t stream) {
  const float* features = (const float*)d_in[0];
  const float* adj      = (const float*)d_in[1];
  const float* W1  = (const float*)d_in[2];
  const float* a1s = (const float*)d_in[3];
  const float* a1d = (const float*)d_in[4];
  const float* W2  = (const float*)d_in[5];
  const float* a2s = (const float*)d_in[6];
  const float* a2d = (const float*)d_in[7];
  const float* W3  = (const float*)d_in[8];
  const float* a3s = (const float*)d_in[9];
  const float* a3d = (const float*)d_in[10];
  float* out = (float*)d_out;

  char* ws = (char*)d_ws;
  size_t off = 0;
  int* nbr_cnt = (int*)(ws + off); off += (size_t)NODES * 4;
  int* nbr     = (int*)(ws + off); off += (size_t)NODES * MAXNBR * 4;
  float* Wh    = (float*)(ws + off); off += (size_t)NODES * FOUT * 4;
  _Float16* Wh16 = (_Float16*)(ws + off); off += (size_t)NODES * FOUT * 2;
  float* sbuf  = (float*)(ws + off); off += (size_t)HEADS * NODES * 4;
  float* dbuf  = (float*)(ws + off); off += (size_t)HEADS * NODES * 4;
  _Float16* Ac = (_Float16*)(ws + off); off += (size_t)NODES * 3 * 512 * 2;
  _Float16* Bc1 = (_Float16*)(ws + off); off += (size_t)FOUT * 3 * 256 * 2;
  _Float16* Bc2 = (_Float16*)(ws + off); off += (size_t)FOUT * 3 * 512 * 2;
  _Float16* Bc3 = (_Float16*)(ws + off); off += (size_t)FOUT * 3 * 512 * 2;

  prep_kernel<<<2368, 256, 0, stream>>>(adj, nbr_cnt, nbr, features, Ac,
                                        W1, W2, W3, Bc1, Bc2, Bc3);

  dim3 gg(HEADS, NODES / 64);

  // ---- layer 1 (K=256, Keff=768): fp32 Wh gather ----
  gemm_mfma<0><<<gg, 256, 0, stream>>>(Ac, Bc1, Wh, Wh16, a1s, a1d, sbuf, dbuf, 768);
  attn_kernel<1, 0><<<NODES, 512, 0, stream>>>(nbr_cnt, nbr, sbuf, dbuf, Wh, Wh16, out, Ac);
  // ---- layer 2 (K=512, Keff=1536): fp16 Wh gather ----
  gemm_mfma<1><<<gg, 256, 0, stream>>>(Ac, Bc2, Wh, Wh16, a2s, a2d, sbuf, dbuf, 1536);
  attn_kernel<1, 1><<<NODES, 512, 0, stream>>>(nbr_cnt, nbr, sbuf, dbuf, Wh, Wh16, out, Ac);
  // ---- layer 3 (K=512, Keff=1536): fp16 Wh gather ----
  gemm_mfma<1><<<gg, 256, 0, stream>>>(Ac, Bc3, Wh, Wh16, a3s, a3d, sbuf, dbuf, 1536);
  attn_kernel<0, 1><<<NODES, 512, 0, stream>>>(nbr_cnt, nbr, sbuf, dbuf, Wh, Wh16, out, Ac);
}

// Round 8
// 137.628 us; speedup vs baseline: 2.6442x; 1.2089x over previous
//
#include <hip/hip_runtime.h>
#include <hip/hip_bf16.h>
#include <math.h>

// GAT, 3 layers, N=4096, H=8, O=64, F_in=256 then 512.
// Sparse softmax over ~1%-dense adj (+self loops) is EXACT vs masked dense.
//
// R2: GEMM on MFMA via exact fp16 hi/lo split (layer 1: Keff=3K).
// R3: build_nbr float4-vectorized; convA fused into attn epilogue.
// R4: attn gather unrolled; dead stores removed; s/d fused into gemm.
// R5: gather x4 chains; all prep fused into one grid-partitioned kernel.
// R6: layers 2-3 gather Wh in fp16 (halves dominant L2-miss traffic).
// R7: layers 2-3 GEMMs are PLAIN fp16 (Keff=512, not 1536): their inputs
//     have rms~0.15 so fp16 rounding adds ~2e-5 std (<<1.6e-3 margin).
//     Ac becomes compact [4096][512] hi-only; attn/convW write 1/3 bytes.

#define NODES 4096
#define HEADS 8
#define HID   64
#define FOUT  512   // HEADS*HID
#define MAXNBR 128

typedef _Float16 half8 __attribute__((ext_vector_type(8)));
typedef _Float16 half4 __attribute__((ext_vector_type(4)));
typedef float f32x4 __attribute__((ext_vector_type(4)));

// ---------------------------------------------------------------------------
// device helpers for the fused prep kernel
// ---------------------------------------------------------------------------
__device__ inline void conv_a_elem(const float* __restrict__ in,
                                   _Float16* __restrict__ out, int K, int id) {
  // layer-1 A: [Ah | Al | Ah], row stride 3K
  int perRow = K >> 2;
  int m = id / perRow, c = (id - m * perRow) * 4;
  float4 v = *(const float4*)(in + (size_t)m * K + c);
  half4 hi, lo;
  hi[0] = (_Float16)v.x; lo[0] = (_Float16)(v.x - (float)hi[0]);
  hi[1] = (_Float16)v.y; lo[1] = (_Float16)(v.y - (float)hi[1]);
  hi[2] = (_Float16)v.z; lo[2] = (_Float16)(v.z - (float)hi[2]);
  hi[3] = (_Float16)v.w; lo[3] = (_Float16)(v.w - (float)hi[3]);
  _Float16* rb = out + (size_t)m * 3 * K;
  *(half4*)(rb + c)         = hi;
  *(half4*)(rb + K + c)     = lo;
  *(half4*)(rb + 2 * K + c) = hi;
}

__device__ inline void conv_w_elem(const float* __restrict__ W,
                                   _Float16* __restrict__ Bc, int K, int id,
                                   bool split3) {
  int n = id & 63;
  int r = id >> 6;
  int kchunks = K >> 3;
  int kc = r % kchunks, h = r / kchunks;
  int k0 = kc * 8;
  half8 hi, lo;
#pragma unroll
  for (int i = 0; i < 8; ++i) {
    float w = W[((size_t)h * K + k0 + i) * 64 + n];
    _Float16 wh = (_Float16)w;
    hi[i] = wh;
    lo[i] = (_Float16)(w - (float)wh);
  }
  if (split3) {
    _Float16* rb = Bc + (size_t)(h * 64 + n) * (3 * K);
    *(half8*)(rb + k0)         = hi;
    *(half8*)(rb + K + k0)     = hi;
    *(half8*)(rb + 2 * K + k0) = lo;
  } else {
    _Float16* rb = Bc + (size_t)(h * 64 + n) * K;
    *(half8*)(rb + k0) = hi;
  }
}

// ---------------------------------------------------------------------------
// Fused prep: block-range partitioned.
//   [0,1024)      build_nbr       [1024,2048) convA(features, split)
//   [2048,2112)   convW1 (split3) [2112,2240) convW2 (hi)  [2240,2368) convW3
// ---------------------------------------------------------------------------
__global__ __launch_bounds__(256) void prep_kernel(
    const float* __restrict__ adj, int* __restrict__ nbr_cnt,
    int* __restrict__ nbr, const float* __restrict__ features,
    _Float16* __restrict__ Ac1,
    const float* __restrict__ W1, const float* __restrict__ W2,
    const float* __restrict__ W3, _Float16* __restrict__ Bc1,
    _Float16* __restrict__ Bc2, _Float16* __restrict__ Bc3) {
  const int b = blockIdx.x;
  if (b < 1024) {
    int wave = b * 4 + (threadIdx.x >> 6);
    int lane = threadIdx.x & 63;
    const float4* arow = (const float4*)(adj + (size_t)wave * NODES);
    int* lst = nbr + (size_t)wave * MAXNBR;
    int base = 0;
    float4 a = arow[lane];
#pragma unroll 4
    for (int it = 0; it < 16; ++it) {
      float4 cur = a;
      if (it + 1 < 16) a = arow[(it + 1) * 64 + lane];
      const int colbase = it * 256 + lane * 4;
#pragma unroll
      for (int c = 0; c < 4; ++c) {
        float v = (c == 0) ? cur.x : (c == 1) ? cur.y : (c == 2) ? cur.z : cur.w;
        unsigned long long mask = __ballot(v > 0.0f);
        if (v > 0.0f) {
          int pos = base + __popcll(mask & ((1ull << lane) - 1ull));
          if (pos < MAXNBR) lst[pos] = colbase + c;
        }
        base += __popcll(mask);
      }
    }
    if (lane == 0) nbr_cnt[wave] = base < MAXNBR ? base : MAXNBR;
  } else if (b < 2048) {
    conv_a_elem(features, Ac1, 256, (b - 1024) * 256 + threadIdx.x);
  } else if (b < 2112) {
    conv_w_elem(W1, Bc1, 256, (b - 2048) * 256 + threadIdx.x, true);
  } else if (b < 2240) {
    conv_w_elem(W2, Bc2, 512, (b - 2112) * 256 + threadIdx.x, false);
  } else {
    conv_w_elem(W3, Bc3, 512, (b - 2240) * 256 + threadIdx.x, false);
  }
}

// ---------------------------------------------------------------------------
// C = A[4096,Keff] * B[512,Keff]^T. 64x64 tile, BK=32, 4 waves, 2x2 frags.
// F16OUT=0: write fp32 C.  F16OUT=1: write fp16 C16.
// Fused epilogue: s[h,m], d[h,m] from accumulators.
// ---------------------------------------------------------------------------
template <int F16OUT>
__global__ __launch_bounds__(256) void gemm_mfma(
    const _Float16* __restrict__ A,   // [4096][Keff]
    const _Float16* __restrict__ B,   // [512][Keff]  (n-major)
    float* __restrict__ C,            // [4096][512]   (F16OUT=0)
    _Float16* __restrict__ C16,       // [4096][512]   (F16OUT=1)
    const float* __restrict__ a_src,  // [8][64]
    const float* __restrict__ a_dst,  // [8][64]
    float* __restrict__ sbuf,         // [8][4096]
    float* __restrict__ dbuf,         // [8][4096]
    int Keff) {
  __shared__ _Float16 As[64 * 40];
  __shared__ _Float16 Bs[64 * 40];
  __shared__ float sS[2][64];
  __shared__ float sD[2][64];

  const int t    = threadIdx.x;
  const int m0   = blockIdx.y * 64;
  const int n0   = blockIdx.x * 64;
  const int h    = blockIdx.x;
  const int w    = t >> 6;
  const int lane = t & 63;
  const int wr   = (w >> 1) * 32;
  const int wc   = (w & 1) * 32;
  const int lr   = lane & 15;
  const int lk   = (lane >> 4) * 8;

  const int sr = t >> 2;
  const int sc = (t & 3) * 8;
  const _Float16* gA = A + (size_t)(m0 + sr) * Keff + sc;
  const _Float16* gB = B + (size_t)(n0 + sr) * Keff + sc;

  f32x4 acc00 = {}, acc01 = {}, acc10 = {}, acc11 = {};

  half8 av = *(const half8*)(gA);
  half8 bv = *(const half8*)(gB);

  for (int k0 = 0; k0 < Keff; k0 += 32) {
    __syncthreads();
    *(half8*)(&As[sr * 40 + sc]) = av;
    *(half8*)(&Bs[sr * 40 + sc]) = bv;
    __syncthreads();
    if (k0 + 32 < Keff) {
      av = *(const half8*)(gA + k0 + 32);
      bv = *(const half8*)(gB + k0 + 32);
    }
    half8 a0 = *(const half8*)(&As[(wr + lr) * 40 + lk]);
    half8 a1 = *(const half8*)(&As[(wr + 16 + lr) * 40 + lk]);
    half8 b0 = *(const half8*)(&Bs[(wc + lr) * 40 + lk]);
    half8 b1 = *(const half8*)(&Bs[(wc + 16 + lr) * 40 + lk]);
    acc00 = __builtin_amdgcn_mfma_f32_16x16x32_f16(a0, b0, acc00, 0, 0, 0);
    acc01 = __builtin_amdgcn_mfma_f32_16x16x32_f16(a0, b1, acc01, 0, 0, 0);
    acc10 = __builtin_amdgcn_mfma_f32_16x16x32_f16(a1, b0, acc10, 0, 0, 0);
    acc11 = __builtin_amdgcn_mfma_f32_16x16x32_f16(a1, b1, acc11, 0, 0, 0);
  }

  // C/D layout: col = lane&15, row = (lane>>4)*4 + reg  [m89/m91 verified]
  const int cm = (lane >> 4) * 4;
#pragma unroll
  for (int j = 0; j < 4; ++j) {
    int m  = m0 + wr + cm + j;
    int m2 = m + 16;
    if constexpr (F16OUT) {
      C16[(size_t)m * FOUT + n0 + wc + lr]       = (_Float16)acc00[j];
      C16[(size_t)m * FOUT + n0 + wc + 16 + lr]  = (_Float16)acc01[j];
      C16[(size_t)m2 * FOUT + n0 + wc + lr]      = (_Float16)acc10[j];
      C16[(size_t)m2 * FOUT + n0 + wc + 16 + lr] = (_Float16)acc11[j];
    } else {
      C[(size_t)m * FOUT + n0 + wc + lr]       = acc00[j];
      C[(size_t)m * FOUT + n0 + wc + 16 + lr]  = acc01[j];
      C[(size_t)m2 * FOUT + n0 + wc + lr]      = acc10[j];
      C[(size_t)m2 * FOUT + n0 + wc + 16 + lr] = acc11[j];
    }
  }

  // fused s/d epilogue (fp32-exact from accumulators)
  const float as0 = a_src[(h << 6) + wc + lr];
  const float as1 = a_src[(h << 6) + wc + 16 + lr];
  const float ad0 = a_dst[(h << 6) + wc + lr];
  const float ad1 = a_dst[(h << 6) + wc + 16 + lr];
  float ps[8], pd[8];
#pragma unroll
  for (int j = 0; j < 4; ++j) {
    ps[j]     = acc00[j] * as0 + acc01[j] * as1;
    ps[4 + j] = acc10[j] * as0 + acc11[j] * as1;
    pd[j]     = acc00[j] * ad0 + acc01[j] * ad1;
    pd[4 + j] = acc10[j] * ad0 + acc11[j] * ad1;
  }
#pragma unroll
  for (int off = 1; off < 16; off <<= 1) {
#pragma unroll
    for (int j = 0; j < 8; ++j) {
      ps[j] += __shfl_xor(ps[j], off);
      pd[j] += __shfl_xor(pd[j], off);
    }
  }
  if (lr == 0) {
#pragma unroll
    for (int j = 0; j < 4; ++j) {
      sS[w & 1][wr + cm + j]      = ps[j];
      sS[w & 1][wr + 16 + cm + j] = ps[4 + j];
      sD[w & 1][wr + cm + j]      = pd[j];
      sD[w & 1][wr + 16 + cm + j] = pd[4 + j];
    }
  }
  __syncthreads();
  if (t < 64) {
    sbuf[(size_t)h * NODES + m0 + t] = sS[0][t] + sS[1][t];
    dbuf[(size_t)h * NODES + m0 + t] = sD[0][t] + sD[1][t];
  }
}

// ---------------------------------------------------------------------------
// Sparse masked softmax + PV + ELU.
// F16IN=0: gather fp32 Wh (4x float4 chains). F16IN=1: fp16 Wh16 (2x half8).
// WRITE_AC: write next layer's A as compact fp16 hi-only [4096][512].
// ---------------------------------------------------------------------------
template <int WRITE_AC, int F16IN>
__global__ __launch_bounds__(512) void attn_kernel(
    const int* __restrict__ nbr_cnt, const int* __restrict__ nbr,
    const float* __restrict__ s, const float* __restrict__ d,
    const float* __restrict__ Wh, const _Float16* __restrict__ Wh16,
    float* __restrict__ out, _Float16* __restrict__ Ac) {
  __shared__ int   lst_lds[MAXNBR];
  __shared__ float w_lds[HEADS][MAXNBR];

  const int i    = blockIdx.x;
  const int tid  = threadIdx.x;
  const int h    = tid >> 6;
  const int lane = tid & 63;
  const int cnt  = nbr_cnt[i];

  if (tid < MAXNBR)
    lst_lds[tid] = (tid < cnt) ? nbr[(size_t)i * MAXNBR + tid] : i;
  __syncthreads();

  const float s_i = s[(size_t)h * NODES + i];
  const float* dh = d + (size_t)h * NODES;
  float e0 = -1e30f, e1 = -1e30f;
  if (lane < cnt) {
    float e = s_i + dh[lst_lds[lane]];
    e0 = (e >= 0.0f) ? e : 0.2f * e;
  }
  if (lane + 64 < cnt) {
    float e = s_i + dh[lst_lds[lane + 64]];
    e1 = (e >= 0.0f) ? e : 0.2f * e;
  }
  float m = fmaxf(e0, e1);
#pragma unroll
  for (int off = 32; off; off >>= 1) m = fmaxf(m, __shfl_xor(m, off));
  float w0 = (lane < cnt) ? __expf(e0 - m) : 0.0f;
  float w1 = (lane + 64 < cnt) ? __expf(e1 - m) : 0.0f;
  w_lds[h][lane]      = w0;
  w_lds[h][lane + 64] = w1;
  float den = w0 + w1;
#pragma unroll
  for (int off = 32; off; off >>= 1) den += __shfl_xor(den, off);
  const float rden = 1.0f / den;
  __syncthreads();

  if constexpr (F16IN) {
    const int g  = lane >> 3;
    const int d8 = (lane & 7) * 8;
    const int cnt16 = (cnt + 15) & ~15;
    float aA[8] = {}, aB[8] = {};
    for (int t0 = 0; t0 < cnt16; t0 += 16) {
      const int ta = t0 + g;
      const int tb = ta + 8;
      const int ja = lst_lds[ta], jb = lst_lds[tb];
      const float wa = w_lds[h][ta], wb = w_lds[h][tb];
      const half8 va = *(const half8*)(Wh16 + (size_t)ja * FOUT + h * HID + d8);
      const half8 vb = *(const half8*)(Wh16 + (size_t)jb * FOUT + h * HID + d8);
#pragma unroll
      for (int q = 0; q < 8; ++q) {
        aA[q] += wa * (float)va[q];
        aB[q] += wb * (float)vb[q];
      }
    }
    float acc[8];
#pragma unroll
    for (int q = 0; q < 8; ++q) acc[q] = aA[q] + aB[q];
#pragma unroll
    for (int off = 8; off <= 32; off <<= 1)
#pragma unroll
      for (int q = 0; q < 8; ++q) acc[q] += __shfl_xor(acc[q], off);

    if (lane < 8) {
      float o[8];
#pragma unroll
      for (int q = 0; q < 8; ++q) {
        float v = acc[q] * rden;
        o[q] = (v > 0.0f) ? v : (__expf(v) - 1.0f);
      }
      if (WRITE_AC) {
        half8 hi;
#pragma unroll
        for (int q = 0; q < 8; ++q) hi[q] = (_Float16)o[q];
        *(half8*)(Ac + (size_t)i * FOUT + h * HID + d8) = hi;
      } else {
        float* ob = out + (size_t)i * FOUT + h * HID + d8;
        *(float4*)(ob)     = make_float4(o[0], o[1], o[2], o[3]);
        *(float4*)(ob + 4) = make_float4(o[4], o[5], o[6], o[7]);
      }
    }
  } else {
    const int g  = lane >> 4;
    const int dq = (lane & 15) * 4;
    const int cnt16 = (cnt + 15) & ~15;
    float aAx = 0.f, aAy = 0.f, aAz = 0.f, aAw = 0.f;
    float aBx = 0.f, aBy = 0.f, aBz = 0.f, aBw = 0.f;
    float aCx = 0.f, aCy = 0.f, aCz = 0.f, aCw = 0.f;
    float aDx = 0.f, aDy = 0.f, aDz = 0.f, aDw = 0.f;
    for (int t0 = 0; t0 < cnt16; t0 += 16) {
      const int ta = t0 + g;
      const int tb = ta + 4;
      const int tc = ta + 8;
      const int td = ta + 12;
      const int ja = lst_lds[ta], jb = lst_lds[tb];
      const int jc = lst_lds[tc], jd = lst_lds[td];
      const float wa = w_lds[h][ta], wb = w_lds[h][tb];
      const float wc = w_lds[h][tc], wd = w_lds[h][td];
      const float4 va = *(const float4*)(Wh + (size_t)ja * FOUT + h * HID + dq);
      const float4 vb = *(const float4*)(Wh + (size_t)jb * FOUT + h * HID + dq);
      const float4 vc = *(const float4*)(Wh + (size_t)jc * FOUT + h * HID + dq);
      const float4 vd = *(const float4*)(Wh + (size_t)jd * FOUT + h * HID + dq);
      aAx += wa * va.x; aAy += wa * va.y; aAz += wa * va.z; aAw += wa * va.w;
      aBx += wb * vb.x; aBy += wb * vb.y; aBz += wb * vb.z; aBw += wb * vb.w;
      aCx += wc * vc.x; aCy += wc * vc.y; aCz += wc * vc.z; aCw += wc * vc.w;
      aDx += wd * vd.x; aDy += wd * vd.y; aDz += wd * vd.z; aDw += wd * vd.w;
    }
    float ax = (aAx + aBx) + (aCx + aDx);
    float ay = (aAy + aBy) + (aCy + aDy);
    float az = (aAz + aBz) + (aCz + aDz);
    float aw = (aAw + aBw) + (aCw + aDw);
    ax += __shfl_xor(ax, 16); ax += __shfl_xor(ax, 32);
    ay += __shfl_xor(ay, 16); ay += __shfl_xor(ay, 32);
    az += __shfl_xor(az, 16); az += __shfl_xor(az, 32);
    aw += __shfl_xor(aw, 16); aw += __shfl_xor(aw, 32);

    if (lane < 16) {
      float4 o;
      o.x = ax * rden; o.y = ay * rden; o.z = az * rden; o.w = aw * rden;
      o.x = (o.x > 0.0f) ? o.x : (__expf(o.x) - 1.0f);
      o.y = (o.y > 0.0f) ? o.y : (__expf(o.y) - 1.0f);
      o.z = (o.z > 0.0f) ? o.z : (__expf(o.z) - 1.0f);
      o.w = (o.w > 0.0f) ? o.w : (__expf(o.w) - 1.0f);
      if (WRITE_AC) {
        half4 hi;
        hi[0] = (_Float16)o.x; hi[1] = (_Float16)o.y;
        hi[2] = (_Float16)o.z; hi[3] = (_Float16)o.w;
        *(half4*)(Ac + (size_t)i * FOUT + h * HID + dq) = hi;
      } else {
        *(float4*)(out + (size_t)i * FOUT + h * HID + dq) = o;
      }
    }
  }
}

// ---------------------------------------------------------------------------
extern "C" void kernel_launch(void* const* d_in, const int* in_sizes, int n_in,
                              void* d_out, int out_size, void* d_ws,
                              size_t ws_size, hipStream_t stream) {
  const float* features = (const float*)d_in[0];
  const float* adj      = (const float*)d_in[1];
  const float* W1  = (const float*)d_in[2];
  const float* a1s = (const float*)d_in[3];
  const float* a1d = (const float*)d_in[4];
  const float* W2  = (const float*)d_in[5];
  const float* a2s = (const float*)d_in[6];
  const float* a2d = (const float*)d_in[7];
  const float* W3  = (const float*)d_in[8];
  const float* a3s = (const float*)d_in[9];
  const float* a3d = (const float*)d_in[10];
  float* out = (float*)d_out;

  char* ws = (char*)d_ws;
  size_t off = 0;
  int* nbr_cnt = (int*)(ws + off); off += (size_t)NODES * 4;
  int* nbr     = (int*)(ws + off); off += (size_t)NODES * MAXNBR * 4;
  float* Wh    = (float*)(ws + off); off += (size_t)NODES * FOUT * 4;
  _Float16* Wh16 = (_Float16*)(ws + off); off += (size_t)NODES * FOUT * 2;
  float* sbuf  = (float*)(ws + off); off += (size_t)HEADS * NODES * 4;
  float* dbuf  = (float*)(ws + off); off += (size_t)HEADS * NODES * 4;
  _Float16* Ac1 = (_Float16*)(ws + off); off += (size_t)NODES * 768 * 2;   // layer-1 split A
  _Float16* Ac2 = (_Float16*)(ws + off); off += (size_t)NODES * FOUT * 2;  // layers 2/3 plain A
  _Float16* Bc1 = (_Float16*)(ws + off); off += (size_t)FOUT * 768 * 2;
  _Float16* Bc2 = (_Float16*)(ws + off); off += (size_t)FOUT * 512 * 2;
  _Float16* Bc3 = (_Float16*)(ws + off); off += (size_t)FOUT * 512 * 2;

  prep_kernel<<<2368, 256, 0, stream>>>(adj, nbr_cnt, nbr, features, Ac1,
                                        W1, W2, W3, Bc1, Bc2, Bc3);

  dim3 gg(HEADS, NODES / 64);

  // ---- layer 1 (Keff=768, exact split): fp32 Wh gather ----
  gemm_mfma<0><<<gg, 256, 0, stream>>>(Ac1, Bc1, Wh, Wh16, a1s, a1d, sbuf, dbuf, 768);
  attn_kernel<1, 0><<<NODES, 512, 0, stream>>>(nbr_cnt, nbr, sbuf, dbuf, Wh, Wh16, out, Ac2);
  // ---- layer 2 (Keff=512, plain fp16): fp16 Wh gather ----
  gemm_mfma<1><<<gg, 256, 0, stream>>>(Ac2, Bc2, Wh, Wh16, a2s, a2d, sbuf, dbuf, 512);
  attn_kernel<1, 1><<<NODES, 512, 0, stream>>>(nbr_cnt, nbr, sbuf, dbuf, Wh, Wh16, out, Ac2);
  // ---- layer 3 (Keff=512, plain fp16): fp16 Wh gather ----
  gemm_mfma<1><<<gg, 256, 0, stream>>>(Ac2, Bc3, Wh, Wh16, a3s, a3d, sbuf, dbuf, 512);
  attn_kernel<0, 1><<<NODES, 512, 0, stream>>>(nbr_cnt, nbr, sbuf, dbuf, Wh, Wh16, out, Ac2);
}

// Round 9
// 128.741 us; speedup vs baseline: 2.8267x; 1.0690x over previous
//
#include <hip/hip_runtime.h>
#include <hip/hip_bf16.h>
#include <math.h>

// GAT, 3 layers, N=4096, H=8, O=64, F_in=256 then 512.
// Sparse softmax over ~1%-dense adj (+self loops) is EXACT vs masked dense.
//
// R2: GEMM on MFMA via exact fp16 hi/lo split (layer 1: Keff=3K).
// R3-R5: vectorized build_nbr; fused prep; fused s/d epilogue; x4 MLP gather.
// R6-R7: fp16 Wh gather + plain-fp16 GEMMs for layers 2-3 (error budget ok).
// R8(this): fp32 Wh deleted entirely — ALL layers gather fp16 Wh16
//     (layer-1 rounding: ~1e-4 std into h1, <=7e-4 worst-case at out);
//     gemm writes only the 4MB fp16 C16; build_nbr prefetch depth 2.

#define NODES 4096
#define HEADS 8
#define HID   64
#define FOUT  512   // HEADS*HID
#define MAXNBR 128

typedef _Float16 half8 __attribute__((ext_vector_type(8)));
typedef _Float16 half4 __attribute__((ext_vector_type(4)));
typedef float f32x4 __attribute__((ext_vector_type(4)));

// ---------------------------------------------------------------------------
// device helpers for the fused prep kernel
// ---------------------------------------------------------------------------
__device__ inline void conv_a_elem(const float* __restrict__ in,
                                   _Float16* __restrict__ out, int K, int id) {
  // layer-1 A: [Ah | Al | Ah], row stride 3K  (exact split GEMM)
  int perRow = K >> 2;
  int m = id / perRow, c = (id - m * perRow) * 4;
  float4 v = *(const float4*)(in + (size_t)m * K + c);
  half4 hi, lo;
  hi[0] = (_Float16)v.x; lo[0] = (_Float16)(v.x - (float)hi[0]);
  hi[1] = (_Float16)v.y; lo[1] = (_Float16)(v.y - (float)hi[1]);
  hi[2] = (_Float16)v.z; lo[2] = (_Float16)(v.z - (float)hi[2]);
  hi[3] = (_Float16)v.w; lo[3] = (_Float16)(v.w - (float)hi[3]);
  _Float16* rb = out + (size_t)m * 3 * K;
  *(half4*)(rb + c)         = hi;
  *(half4*)(rb + K + c)     = lo;
  *(half4*)(rb + 2 * K + c) = hi;
}

__device__ inline void conv_w_elem(const float* __restrict__ W,
                                   _Float16* __restrict__ Bc, int K, int id,
                                   bool split3) {
  int n = id & 63;
  int r = id >> 6;
  int kchunks = K >> 3;
  int kc = r % kchunks, h = r / kchunks;
  int k0 = kc * 8;
  half8 hi, lo;
#pragma unroll
  for (int i = 0; i < 8; ++i) {
    float w = W[((size_t)h * K + k0 + i) * 64 + n];
    _Float16 wh = (_Float16)w;
    hi[i] = wh;
    lo[i] = (_Float16)(w - (float)wh);
  }
  if (split3) {
    _Float16* rb = Bc + (size_t)(h * 64 + n) * (3 * K);
    *(half8*)(rb + k0)         = hi;
    *(half8*)(rb + K + k0)     = hi;
    *(half8*)(rb + 2 * K + k0) = lo;
  } else {
    _Float16* rb = Bc + (size_t)(h * 64 + n) * K;
    *(half8*)(rb + k0) = hi;
  }
}

// ---------------------------------------------------------------------------
// Fused prep: block-range partitioned.
//   [0,1024)      build_nbr       [1024,2048) convA(features, split)
//   [2048,2112)   convW1 (split3) [2112,2240) convW2 (hi)  [2240,2368) convW3
// ---------------------------------------------------------------------------
__global__ __launch_bounds__(256) void prep_kernel(
    const float* __restrict__ adj, int* __restrict__ nbr_cnt,
    int* __restrict__ nbr, const float* __restrict__ features,
    _Float16* __restrict__ Ac1,
    const float* __restrict__ W1, const float* __restrict__ W2,
    const float* __restrict__ W3, _Float16* __restrict__ Bc1,
    _Float16* __restrict__ Bc2, _Float16* __restrict__ Bc3) {
  const int b = blockIdx.x;
  if (b < 1024) {
    int wave = b * 4 + (threadIdx.x >> 6);
    int lane = threadIdx.x & 63;
    const float4* arow = (const float4*)(adj + (size_t)wave * NODES);
    int* lst = nbr + (size_t)wave * MAXNBR;
    int base = 0;
    float4 a0 = arow[lane];
    float4 a1 = arow[64 + lane];
#pragma unroll 4
    for (int it = 0; it < 16; ++it) {
      float4 cur = a0;
      a0 = a1;
      if (it + 2 < 16) a1 = arow[(it + 2) * 64 + lane];
      const int colbase = it * 256 + lane * 4;
#pragma unroll
      for (int c = 0; c < 4; ++c) {
        float v = (c == 0) ? cur.x : (c == 1) ? cur.y : (c == 2) ? cur.z : cur.w;
        unsigned long long mask = __ballot(v > 0.0f);
        if (v > 0.0f) {
          int pos = base + __popcll(mask & ((1ull << lane) - 1ull));
          if (pos < MAXNBR) lst[pos] = colbase + c;
        }
        base += __popcll(mask);
      }
    }
    if (lane == 0) nbr_cnt[wave] = base < MAXNBR ? base : MAXNBR;
  } else if (b < 2048) {
    conv_a_elem(features, Ac1, 256, (b - 1024) * 256 + threadIdx.x);
  } else if (b < 2112) {
    conv_w_elem(W1, Bc1, 256, (b - 2048) * 256 + threadIdx.x, true);
  } else if (b < 2240) {
    conv_w_elem(W2, Bc2, 512, (b - 2112) * 256 + threadIdx.x, false);
  } else {
    conv_w_elem(W3, Bc3, 512, (b - 2240) * 256 + threadIdx.x, false);
  }
}

// ---------------------------------------------------------------------------
// C16[4096,512] = A[4096,Keff] * B[512,Keff]^T (fp16 in, fp32 accum, fp16 out)
// 64x64 tile, BK=32, 4 waves, 2x2 frags of 16x16x32 MFMA.
// Fused epilogue: s[h,m], d[h,m] computed fp32-exact from accumulators.
// ---------------------------------------------------------------------------
__global__ __launch_bounds__(256) void gemm_mfma(
    const _Float16* __restrict__ A,   // [4096][Keff]
    const _Float16* __restrict__ B,   // [512][Keff]  (n-major)
    _Float16* __restrict__ C16,       // [4096][512]
    const float* __restrict__ a_src,  // [8][64]
    const float* __restrict__ a_dst,  // [8][64]
    float* __restrict__ sbuf,         // [8][4096]
    float* __restrict__ dbuf,         // [8][4096]
    int Keff) {
  __shared__ _Float16 As[64 * 40];
  __shared__ _Float16 Bs[64 * 40];
  __shared__ float sS[2][64];
  __shared__ float sD[2][64];

  const int t    = threadIdx.x;
  const int m0   = blockIdx.y * 64;
  const int n0   = blockIdx.x * 64;
  const int h    = blockIdx.x;
  const int w    = t >> 6;
  const int lane = t & 63;
  const int wr   = (w >> 1) * 32;
  const int wc   = (w & 1) * 32;
  const int lr   = lane & 15;
  const int lk   = (lane >> 4) * 8;

  const int sr = t >> 2;
  const int sc = (t & 3) * 8;
  const _Float16* gA = A + (size_t)(m0 + sr) * Keff + sc;
  const _Float16* gB = B + (size_t)(n0 + sr) * Keff + sc;

  f32x4 acc00 = {}, acc01 = {}, acc10 = {}, acc11 = {};

  half8 av = *(const half8*)(gA);
  half8 bv = *(const half8*)(gB);

  for (int k0 = 0; k0 < Keff; k0 += 32) {
    __syncthreads();
    *(half8*)(&As[sr * 40 + sc]) = av;
    *(half8*)(&Bs[sr * 40 + sc]) = bv;
    __syncthreads();
    if (k0 + 32 < Keff) {
      av = *(const half8*)(gA + k0 + 32);
      bv = *(const half8*)(gB + k0 + 32);
    }
    half8 a0 = *(const half8*)(&As[(wr + lr) * 40 + lk]);
    half8 a1 = *(const half8*)(&As[(wr + 16 + lr) * 40 + lk]);
    half8 b0 = *(const half8*)(&Bs[(wc + lr) * 40 + lk]);
    half8 b1 = *(const half8*)(&Bs[(wc + 16 + lr) * 40 + lk]);
    acc00 = __builtin_amdgcn_mfma_f32_16x16x32_f16(a0, b0, acc00, 0, 0, 0);
    acc01 = __builtin_amdgcn_mfma_f32_16x16x32_f16(a0, b1, acc01, 0, 0, 0);
    acc10 = __builtin_amdgcn_mfma_f32_16x16x32_f16(a1, b0, acc10, 0, 0, 0);
    acc11 = __builtin_amdgcn_mfma_f32_16x16x32_f16(a1, b1, acc11, 0, 0, 0);
  }

  // C/D layout: col = lane&15, row = (lane>>4)*4 + reg  [m89/m91 verified]
  const int cm = (lane >> 4) * 4;
#pragma unroll
  for (int j = 0; j < 4; ++j) {
    int m  = m0 + wr + cm + j;
    int m2 = m + 16;
    C16[(size_t)m * FOUT + n0 + wc + lr]       = (_Float16)acc00[j];
    C16[(size_t)m * FOUT + n0 + wc + 16 + lr]  = (_Float16)acc01[j];
    C16[(size_t)m2 * FOUT + n0 + wc + lr]      = (_Float16)acc10[j];
    C16[(size_t)m2 * FOUT + n0 + wc + 16 + lr] = (_Float16)acc11[j];
  }

  // fused s/d epilogue (fp32-exact from accumulators)
  const float as0 = a_src[(h << 6) + wc + lr];
  const float as1 = a_src[(h << 6) + wc + 16 + lr];
  const float ad0 = a_dst[(h << 6) + wc + lr];
  const float ad1 = a_dst[(h << 6) + wc + 16 + lr];
  float ps[8], pd[8];
#pragma unroll
  for (int j = 0; j < 4; ++j) {
    ps[j]     = acc00[j] * as0 + acc01[j] * as1;
    ps[4 + j] = acc10[j] * as0 + acc11[j] * as1;
    pd[j]     = acc00[j] * ad0 + acc01[j] * ad1;
    pd[4 + j] = acc10[j] * ad0 + acc11[j] * ad1;
  }
#pragma unroll
  for (int off = 1; off < 16; off <<= 1) {
#pragma unroll
    for (int j = 0; j < 8; ++j) {
      ps[j] += __shfl_xor(ps[j], off);
      pd[j] += __shfl_xor(pd[j], off);
    }
  }
  if (lr == 0) {
#pragma unroll
    for (int j = 0; j < 4; ++j) {
      sS[w & 1][wr + cm + j]      = ps[j];
      sS[w & 1][wr + 16 + cm + j] = ps[4 + j];
      sD[w & 1][wr + cm + j]      = pd[j];
      sD[w & 1][wr + 16 + cm + j] = pd[4 + j];
    }
  }
  __syncthreads();
  if (t < 64) {
    sbuf[(size_t)h * NODES + m0 + t] = sS[0][t] + sS[1][t];
    dbuf[(size_t)h * NODES + m0 + t] = sD[0][t] + sD[1][t];
  }
}

// ---------------------------------------------------------------------------
// Sparse masked softmax + PV + ELU. fp16 Wh16 gather (2x half8 chains).
// WRITE_AC=1: write next layer's A as fp16 [4096][512]. =0: fp32 out.
// ---------------------------------------------------------------------------
template <int WRITE_AC>
__global__ __launch_bounds__(512) void attn_kernel(
    const int* __restrict__ nbr_cnt, const int* __restrict__ nbr,
    const float* __restrict__ s, const float* __restrict__ d,
    const _Float16* __restrict__ Wh16,
    float* __restrict__ out, _Float16* __restrict__ Ac) {
  __shared__ int   lst_lds[MAXNBR];
  __shared__ float w_lds[HEADS][MAXNBR];

  const int i    = blockIdx.x;
  const int tid  = threadIdx.x;
  const int h    = tid >> 6;
  const int lane = tid & 63;
  const int cnt  = nbr_cnt[i];

  if (tid < MAXNBR)
    lst_lds[tid] = (tid < cnt) ? nbr[(size_t)i * MAXNBR + tid] : i;
  __syncthreads();

  const float s_i = s[(size_t)h * NODES + i];
  const float* dh = d + (size_t)h * NODES;
  float e0 = -1e30f, e1 = -1e30f;
  if (lane < cnt) {
    float e = s_i + dh[lst_lds[lane]];
    e0 = (e >= 0.0f) ? e : 0.2f * e;
  }
  if (lane + 64 < cnt) {
    float e = s_i + dh[lst_lds[lane + 64]];
    e1 = (e >= 0.0f) ? e : 0.2f * e;
  }
  float m = fmaxf(e0, e1);
#pragma unroll
  for (int off = 32; off; off >>= 1) m = fmaxf(m, __shfl_xor(m, off));
  float w0 = (lane < cnt) ? __expf(e0 - m) : 0.0f;
  float w1 = (lane + 64 < cnt) ? __expf(e1 - m) : 0.0f;
  w_lds[h][lane]      = w0;
  w_lds[h][lane + 64] = w1;
  float den = w0 + w1;
#pragma unroll
  for (int off = 32; off; off >>= 1) den += __shfl_xor(den, off);
  const float rden = 1.0f / den;
  __syncthreads();

  // gather: 8 subgroups of 8 lanes; lane covers 8 dims via half8; 2 chains.
  const int g  = lane >> 3;
  const int d8 = (lane & 7) * 8;
  const int cnt16 = (cnt + 15) & ~15;
  float aA[8] = {}, aB[8] = {};
  for (int t0 = 0; t0 < cnt16; t0 += 16) {
    const int ta = t0 + g;
    const int tb = ta + 8;
    const int ja = lst_lds[ta], jb = lst_lds[tb];
    const float wa = w_lds[h][ta], wb = w_lds[h][tb];
    const half8 va = *(const half8*)(Wh16 + (size_t)ja * FOUT + h * HID + d8);
    const half8 vb = *(const half8*)(Wh16 + (size_t)jb * FOUT + h * HID + d8);
#pragma unroll
    for (int q = 0; q < 8; ++q) {
      aA[q] += wa * (float)va[q];
      aB[q] += wb * (float)vb[q];
    }
  }
  float acc[8];
#pragma unroll
  for (int q = 0; q < 8; ++q) acc[q] = aA[q] + aB[q];
#pragma unroll
  for (int off = 8; off <= 32; off <<= 1)
#pragma unroll
    for (int q = 0; q < 8; ++q) acc[q] += __shfl_xor(acc[q], off);

  if (lane < 8) {
    float o[8];
#pragma unroll
    for (int q = 0; q < 8; ++q) {
      float v = acc[q] * rden;
      o[q] = (v > 0.0f) ? v : (__expf(v) - 1.0f);
    }
    if (WRITE_AC) {
      half8 hi;
#pragma unroll
      for (int q = 0; q < 8; ++q) hi[q] = (_Float16)o[q];
      *(half8*)(Ac + (size_t)i * FOUT + h * HID + d8) = hi;
    } else {
      float* ob = out + (size_t)i * FOUT + h * HID + d8;
      *(float4*)(ob)     = make_float4(o[0], o[1], o[2], o[3]);
      *(float4*)(ob + 4) = make_float4(o[4], o[5], o[6], o[7]);
    }
  }
}

// ---------------------------------------------------------------------------
extern "C" void kernel_launch(void* const* d_in, const int* in_sizes, int n_in,
                              void* d_out, int out_size, void* d_ws,
                              size_t ws_size, hipStream_t stream) {
  const float* features = (const float*)d_in[0];
  const float* adj      = (const float*)d_in[1];
  const float* W1  = (const float*)d_in[2];
  const float* a1s = (const float*)d_in[3];
  const float* a1d = (const float*)d_in[4];
  const float* W2  = (const float*)d_in[5];
  const float* a2s = (const float*)d_in[6];
  const float* a2d = (const float*)d_in[7];
  const float* W3  = (const float*)d_in[8];
  const float* a3s = (const float*)d_in[9];
  const float* a3d = (const float*)d_in[10];
  float* out = (float*)d_out;

  char* ws = (char*)d_ws;
  size_t off = 0;
  int* nbr_cnt = (int*)(ws + off); off += (size_t)NODES * 4;
  int* nbr     = (int*)(ws + off); off += (size_t)NODES * MAXNBR * 4;
  _Float16* Wh16 = (_Float16*)(ws + off); off += (size_t)NODES * FOUT * 2;
  float* sbuf  = (float*)(ws + off); off += (size_t)HEADS * NODES * 4;
  float* dbuf  = (float*)(ws + off); off += (size_t)HEADS * NODES * 4;
  _Float16* Ac1 = (_Float16*)(ws + off); off += (size_t)NODES * 768 * 2;   // layer-1 split A
  _Float16* Ac2 = (_Float16*)(ws + off); off += (size_t)NODES * FOUT * 2;  // layers 2/3 plain A
  _Float16* Bc1 = (_Float16*)(ws + off); off += (size_t)FOUT * 768 * 2;
  _Float16* Bc2 = (_Float16*)(ws + off); off += (size_t)FOUT * 512 * 2;
  _Float16* Bc3 = (_Float16*)(ws + off); off += (size_t)FOUT * 512 * 2;

  prep_kernel<<<2368, 256, 0, stream>>>(adj, nbr_cnt, nbr, features, Ac1,
                                        W1, W2, W3, Bc1, Bc2, Bc3);

  dim3 gg(HEADS, NODES / 64);

  // ---- layer 1 (Keff=768, exact split GEMM; fp16 Wh gather) ----
  gemm_mfma<<<gg, 256, 0, stream>>>(Ac1, Bc1, Wh16, a1s, a1d, sbuf, dbuf, 768);
  attn_kernel<1><<<NODES, 512, 0, stream>>>(nbr_cnt, nbr, sbuf, dbuf, Wh16, out, Ac2);
  // ---- layer 2 (Keff=512, plain fp16) ----
  gemm_mfma<<<gg, 256, 0, stream>>>(Ac2, Bc2, Wh16, a2s, a2d, sbuf, dbuf, 512);
  attn_kernel<1><<<NODES, 512, 0, stream>>>(nbr_cnt, nbr, sbuf, dbuf, Wh16, out, Ac2);
  // ---- layer 3 (Keff=512, plain fp16) ----
  gemm_mfma<<<gg, 256, 0, stream>>>(Ac2, Bc3, Wh16, a3s, a3d, sbuf, dbuf, 512);
  attn_kernel<0><<<NODES, 512, 0, stream>>>(nbr_cnt, nbr, sbuf, dbuf, Wh16, out, Ac2);
}